// Round 1
// baseline (650.031 us; speedup 1.0000x reference)
//
#include <hip/hip_runtime.h>
#include <hip/hip_bf16.h>

#define NN 100000
#define NE 1600000
#define INDIM 48
#define HID 128
#define K2 256
#define BN_EPS 1e-5f

typedef short s8v __attribute__((ext_vector_type(8)));
typedef float f4v __attribute__((ext_vector_type(4)));

__device__ __forceinline__ unsigned short f2bf(float f) {
    __hip_bfloat16 b = __float2bfloat16(f);
    unsigned short u;
    __builtin_memcpy(&u, &b, 2);
    return u;
}
__device__ __forceinline__ float bf2f(unsigned short u) {
    return __uint_as_float(((unsigned)u) << 16);
}

// ---------------- input projection: pass 1, BN1 column stats ----------------
__global__ __launch_bounds__(256) void k_proj_stats(
    const float* __restrict__ x, const float* __restrict__ W1, const float* __restrict__ b1,
    float* __restrict__ colSum, float* __restrict__ colSq) {
  __shared__ float wT[INDIM][HID];        // 24 KB, transposed: bank-conflict-free
  __shared__ float redS[2][HID], redQ[2][HID];
  int tid = threadIdx.x;
  for (int i = tid; i < HID * INDIM; i += 256) {
    int c = i / INDIM, k = i - c * INDIM;
    wT[k][c] = W1[i];
  }
  __syncthreads();
  int c = tid & (HID - 1);
  int rl = tid >> 7;
  float bb = b1[c];
  float sum = 0.f, sq = 0.f;
  for (int r = blockIdx.x * 2 + rl; r < NN; r += gridDim.x * 2) {
    const float4* xr = (const float4*)(x + (size_t)r * INDIM);  // wave-uniform broadcast loads
    float h = bb;
#pragma unroll
    for (int k4 = 0; k4 < INDIM / 4; ++k4) {
      float4 xv = xr[k4];
      h = fmaf(xv.x, wT[4 * k4 + 0][c], h);
      h = fmaf(xv.y, wT[4 * k4 + 1][c], h);
      h = fmaf(xv.z, wT[4 * k4 + 2][c], h);
      h = fmaf(xv.w, wT[4 * k4 + 3][c], h);
    }
    sum += h;
    sq = fmaf(h, h, sq);
  }
  redS[rl][c] = sum;
  redQ[rl][c] = sq;
  __syncthreads();
  if (rl == 0) {
    atomicAdd(&colSum[c], redS[0][c] + redS[1][c]);
    atomicAdd(&colSq[c], redQ[0][c] + redQ[1][c]);
  }
}

// ---------------- BN finalize: a = g*rsqrt(var+eps), b = be - mu*a ----------------
__global__ void k_bn_final(const float* __restrict__ sum, const float* __restrict__ sq,
                           const float* __restrict__ gamma, const float* __restrict__ beta,
                           float* __restrict__ av, float* __restrict__ bv) {
  int c = threadIdx.x;
  float mu = sum[c] * (1.0f / NN);
  float var = fmaxf(sq[c] * (1.0f / NN) - mu * mu, 0.f);
  float a = gamma[c] * rsqrtf(var + BN_EPS);
  av[c] = a;
  bv[c] = beta[c] - mu * a;
}

// ---------------- input projection: pass 2, recompute h, apply BN1+ReLU ----------------
__global__ __launch_bounds__(256) void k_proj_apply(
    const float* __restrict__ x, const float* __restrict__ W1, const float* __restrict__ b1,
    const float* __restrict__ av, const float* __restrict__ bv,
    float* __restrict__ feat, unsigned short* __restrict__ A) {
  __shared__ float wT[INDIM][HID];
  int tid = threadIdx.x;
  for (int i = tid; i < HID * INDIM; i += 256) {
    int c = i / INDIM, k = i - c * INDIM;
    wT[k][c] = W1[i];
  }
  __syncthreads();
  int c = tid & (HID - 1);
  int rl = tid >> 7;
  float bb1 = b1[c];
  float aa = av[c], bb2 = bv[c];
  for (int r = blockIdx.x * 2 + rl; r < NN; r += gridDim.x * 2) {
    const float4* xr = (const float4*)(x + (size_t)r * INDIM);
    float h = bb1;
#pragma unroll
    for (int k4 = 0; k4 < INDIM / 4; ++k4) {
      float4 xv = xr[k4];
      h = fmaf(xv.x, wT[4 * k4 + 0][c], h);
      h = fmaf(xv.y, wT[4 * k4 + 1][c], h);
      h = fmaf(xv.z, wT[4 * k4 + 2][c], h);
      h = fmaf(xv.w, wT[4 * k4 + 3][c], h);
    }
    float f = fmaxf(fmaf(h, aa, bb2), 0.f);
    feat[(size_t)r * HID + c] = f;                 // output 0 (fp32)
    A[(size_t)r * K2 + HID + c] = f2bf(f);         // bf16 copy -> GEMM A cols 128..255
  }
}

// ---------------- CSR build ----------------
__global__ __launch_bounds__(256) void k_degree(const int* __restrict__ ei, int* __restrict__ cnt) {
  int e = blockIdx.x * 256 + threadIdx.x;
  if (e < NE) {
    int d = ei[NE + e];
    d = min(max(d, 0), NN - 1);  // defensive clamp
    atomicAdd(&cnt[d], 1);
  }
}

__global__ __launch_bounds__(1024) void k_scan1(const int* __restrict__ cnt, int* __restrict__ offs,
                                                int* __restrict__ bsum) {
  __shared__ int s[2][1024];
  int tid = threadIdx.x;
  int i = blockIdx.x * 1024 + tid;
  int v = (i < NN) ? cnt[i] : 0;
  s[0][tid] = v;
  __syncthreads();
  int pp = 0;
  for (int d = 1; d < 1024; d <<= 1) {
    int t = s[pp][tid];
    if (tid >= d) t += s[pp][tid - d];
    s[pp ^ 1][tid] = t;
    __syncthreads();
    pp ^= 1;
  }
  int incl = s[pp][tid];
  if (i < NN) offs[i] = incl - v;
  if (tid == 1023) bsum[blockIdx.x] = incl;
}

__global__ void k_scan2(const int* __restrict__ bsum, int* __restrict__ bbase) {
  __shared__ int s[2][128];
  int tid = threadIdx.x;
  const int NB = (NN + 1023) / 1024;  // 98
  int v = (tid < NB) ? bsum[tid] : 0;
  s[0][tid] = v;
  __syncthreads();
  int pp = 0;
  for (int d = 1; d < 128; d <<= 1) {
    int t = s[pp][tid];
    if (tid >= d) t += s[pp][tid - d];
    s[pp ^ 1][tid] = t;
    __syncthreads();
    pp ^= 1;
  }
  bbase[tid] = s[pp][tid] - v;  // exclusive
}

__global__ __launch_bounds__(256) void k_scan3(int* __restrict__ offs, const int* __restrict__ bbase,
                                               int* __restrict__ cur) {
  int i = blockIdx.x * 256 + threadIdx.x;
  if (i < NN) {
    int o = offs[i] + bbase[i >> 10];
    offs[i] = o;
    cur[i] = o;
  }
}

__global__ __launch_bounds__(256) void k_fill(const int* __restrict__ ei, int* __restrict__ cur,
                                              int* __restrict__ csr) {
  int e = blockIdx.x * 256 + threadIdx.x;
  if (e < NE) {
    int d = ei[NE + e];
    d = min(max(d, 0), NN - 1);
    int s = ei[e];
    s = min(max(s, 0), NN - 1);
    int pos = atomicAdd(&cur[d], 1);
    csr[pos] = s;
  }
}

// ---------------- mean aggregation: 32 lanes per node, gathers bf16 feat rows ----------------
// Abuf used for BOTH read (cols 128..255 = feat) and write (cols 0..127 = agg): disjoint addresses.
__global__ __launch_bounds__(256) void k_aggregate(unsigned short* Abuf,
                                                   const int* __restrict__ offs,
                                                   const int* __restrict__ cnt,
                                                   const int* __restrict__ csr) {
  int lane = threadIdx.x & 31;
  int sub = threadIdx.x >> 5;
  int n = blockIdx.x * 8 + sub;
  if (n >= NN) return;
  int beg = offs[n], c = cnt[n];
  float a0 = 0.f, a1 = 0.f, a2 = 0.f, a3 = 0.f;
  for (int j = 0; j < c; ++j) {
    int s = csr[beg + j];  // broadcast across the 32-lane group
    ushort4 v = *(const ushort4*)(Abuf + (size_t)s * K2 + HID + lane * 4);  // 256B/edge contiguous
    a0 += bf2f(v.x);
    a1 += bf2f(v.y);
    a2 += bf2f(v.z);
    a3 += bf2f(v.w);
  }
  float inv = 1.f / fmaxf((float)c, 1.f);
  ushort4 o;
  o.x = f2bf(a0 * inv);
  o.y = f2bf(a1 * inv);
  o.z = f2bf(a2 * inv);
  o.w = f2bf(a3 * inv);
  *(ushort4*)(Abuf + (size_t)n * K2 + lane * 4) = o;
}

// ---------------- bf16 weight prep: Wcat[j][0:128]=Wl[j], [128:256]=Wr[j] ----------------
__global__ __launch_bounds__(256) void k_prep_w(const float* __restrict__ Wl, const float* __restrict__ Wr,
                                                unsigned short* __restrict__ Wcat) {
  int i = blockIdx.x * 256 + threadIdx.x;
  if (i < HID * K2) {
    int j = i >> 8, k = i & (K2 - 1);
    float v = (k < HID) ? Wl[j * HID + k] : Wr[j * HID + (k - HID)];
    Wcat[i] = f2bf(v);
  }
}

// ---------------- MFMA GEMM: sage = A[N,256] @ Wcat[128,256]^T + bl; BN2 stats fused ----------------
#define MT ((NN + 63) / 64)  // 1563 row tiles of 64

__global__ __launch_bounds__(256) void k_gemm(
    const unsigned short* __restrict__ A, const unsigned short* __restrict__ Wcat,
    const float* __restrict__ bl, float* __restrict__ sage,
    float* __restrict__ colSum, float* __restrict__ colSq) {
  __shared__ __align__(16) unsigned short Bsh[64][264];  // 64 cols x 256 k, +8 pad: 33.8 KB
  __shared__ float redS[4][64], redQ[4][64];
  int tid = threadIdx.x;
  int ch = blockIdx.y;  // column half: cols ch*64 .. ch*64+63
  for (int i = tid; i < 64 * 32; i += 256) {
    int j = i >> 5;
    int kg = (i & 31) << 3;
    *(s8v*)&Bsh[j][kg] = *(const s8v*)(Wcat + ((size_t)(ch * 64 + j)) * K2 + kg);
  }
  __syncthreads();
  int w = tid >> 6, l = tid & 63;
  int m16 = l & 15, q = l >> 4;
  float ssum[4] = {0.f, 0.f, 0.f, 0.f}, ssq[4] = {0.f, 0.f, 0.f, 0.f};
  f4v zero4 = {0.f, 0.f, 0.f, 0.f};
  s8v zero8 = {0, 0, 0, 0, 0, 0, 0, 0};
  for (int tile = blockIdx.x; tile < MT; tile += gridDim.x) {
    int row = tile * 64 + w * 16 + m16;  // A-frag row (m = lane&15)
    bool rv = row < NN;
    f4v acc[4];
#pragma unroll
    for (int nt = 0; nt < 4; ++nt) acc[nt] = zero4;
#pragma unroll
    for (int kt = 0; kt < 8; ++kt) {
      s8v a = zero8;
      if (rv) a = *(const s8v*)(A + (size_t)row * K2 + kt * 32 + q * 8);  // k = quad*8+j
#pragma unroll
      for (int nt = 0; nt < 4; ++nt) {
        s8v b = *(const s8v*)(&Bsh[nt * 16 + m16][kt * 32 + q * 8]);  // B[n=lane&15][k]
        acc[nt] = __builtin_amdgcn_mfma_f32_16x16x32_bf16(a, b, acc[nt], 0, 0, 0);
      }
    }
    int rbase = tile * 64 + w * 16 + q * 4;  // C row = quad*4 + reg
#pragma unroll
    for (int nt = 0; nt < 4; ++nt) {
      int col = ch * 64 + nt * 16 + m16;  // C col = lane&15
      float bv = bl[col];
#pragma unroll
      for (int r4 = 0; r4 < 4; ++r4) {
        int rr = rbase + r4;
        if (rr < NN) {
          float v = acc[nt][r4] + bv;
          sage[(size_t)rr * HID + col] = v;
          ssum[nt] += v;
          ssq[nt] = fmaf(v, v, ssq[nt]);
        }
      }
    }
  }
  // reduce BN2 stats: lanes {l, l^16, l^32, l^48} share a column
#pragma unroll
  for (int nt = 0; nt < 4; ++nt) {
    float s = ssum[nt], qq = ssq[nt];
    s += __shfl_xor(s, 16);
    s += __shfl_xor(s, 32);
    qq += __shfl_xor(qq, 16);
    qq += __shfl_xor(qq, 32);
    if (q == 0) {
      redS[w][nt * 16 + m16] = s;
      redQ[w][nt * 16 + m16] = qq;
    }
  }
  __syncthreads();
  if (tid < 64) {
    float s = redS[0][tid] + redS[1][tid] + redS[2][tid] + redS[3][tid];
    float qq = redQ[0][tid] + redQ[1][tid] + redQ[2][tid] + redQ[3][tid];
    atomicAdd(&colSum[ch * 64 + tid], s);
    atomicAdd(&colSq[ch * 64 + tid], qq);
  }
}

// ---------------- BN2 apply, in-place on d_out second half ----------------
__global__ __launch_bounds__(256) void k_bn_apply(float* __restrict__ sage,
                                                  const float* __restrict__ av,
                                                  const float* __restrict__ bv) {
  int i = blockIdx.x * 256 + threadIdx.x;  // float4 index
  if (i < NN * HID / 4) {
    float4 s = ((const float4*)sage)[i];
    int c = (i * 4) & (HID - 1);
    float4 a = *(const float4*)(av + c);
    float4 b = *(const float4*)(bv + c);
    float4 o;
    o.x = fmaf(s.x, a.x, b.x);
    o.y = fmaf(s.y, a.y, b.y);
    o.z = fmaf(s.z, a.z, b.z);
    o.w = fmaf(s.w, a.w, b.w);
    ((float4*)sage)[i] = o;
  }
}

extern "C" void kernel_launch(void* const* d_in, const int* in_sizes, int n_in,
                              void* d_out, int out_size, void* d_ws, size_t ws_size,
                              hipStream_t stream) {
  const float* x   = (const float*)d_in[0];
  const int*   ei  = (const int*)d_in[1];
  const float* W1  = (const float*)d_in[2];
  const float* b1  = (const float*)d_in[3];
  const float* g1  = (const float*)d_in[4];
  const float* be1 = (const float*)d_in[5];
  const float* Wl  = (const float*)d_in[6];
  const float* bl  = (const float*)d_in[7];
  const float* Wr  = (const float*)d_in[8];
  const float* g2  = (const float*)d_in[9];
  const float* be2 = (const float*)d_in[10];

  float* feat_out = (float*)d_out;                      // output 0: feat [NN][HID] fp32
  float* sage     = (float*)d_out + (size_t)NN * HID;   // output 1 region, used for sage then BN'd in place

  size_t off = 0;
  auto alloc = [&](size_t bytes) -> void* {
    void* p = (char*)d_ws + off;
    off += (bytes + 255) & ~(size_t)255;
    return p;
  };
  unsigned short* Abuf   = (unsigned short*)alloc((size_t)NN * K2 * 2);  // [NN][256] bf16: agg|feat
  int*   counts  = (int*)alloc((size_t)NN * 4);
  int*   offs    = (int*)alloc((size_t)NN * 4);
  int*   cursor  = (int*)alloc((size_t)NN * 4);
  int*   csr     = (int*)alloc((size_t)NE * 4);
  int*   bsum    = (int*)alloc(256 * 4);
  int*   bbase   = (int*)alloc(256 * 4);
  float* stats   = (float*)alloc(8 * HID * 4);
  float* colSum1 = stats;
  float* colSq1  = stats + HID;
  float* colSum2 = stats + 2 * HID;
  float* colSq2  = stats + 3 * HID;
  float* a1v     = stats + 4 * HID;
  float* b1v     = stats + 5 * HID;
  float* a2v     = stats + 6 * HID;
  float* b2v     = stats + 7 * HID;
  unsigned short* Wcat = (unsigned short*)alloc((size_t)HID * K2 * 2);

  hipMemsetAsync(counts, 0, (size_t)NN * 4, stream);
  hipMemsetAsync(stats, 0, 4 * HID * 4, stream);

  k_prep_w<<<(HID * K2 + 255) / 256, 256, 0, stream>>>(Wl, Wr, Wcat);
  k_proj_stats<<<1024, 256, 0, stream>>>(x, W1, b1, colSum1, colSq1);
  k_bn_final<<<1, HID, 0, stream>>>(colSum1, colSq1, g1, be1, a1v, b1v);
  k_proj_apply<<<1024, 256, 0, stream>>>(x, W1, b1, a1v, b1v, feat_out, Abuf);
  k_degree<<<(NE + 255) / 256, 256, 0, stream>>>(ei, counts);
  k_scan1<<<(NN + 1023) / 1024, 1024, 0, stream>>>(counts, offs, bsum);
  k_scan2<<<1, 128, 0, stream>>>(bsum, bbase);
  k_scan3<<<(NN + 255) / 256, 256, 0, stream>>>(offs, bbase, cursor);
  k_fill<<<(NE + 255) / 256, 256, 0, stream>>>(ei, cursor, csr);
  k_aggregate<<<(NN + 7) / 8, 256, 0, stream>>>(Abuf, offs, counts, csr);
  k_gemm<<<dim3(512, 2), 256, 0, stream>>>(Abuf, Wcat, bl, sage, colSum2, colSq2);
  k_bn_final<<<1, HID, 0, stream>>>(colSum2, colSq2, g2, be2, a2v, b2v);
  k_bn_apply<<<(NN * HID / 4 + 255) / 256, 256, 0, stream>>>(sage, a2v, b2v);
}

// Round 2
// 473.414 us; speedup vs baseline: 1.3731x; 1.3731x over previous
//
#include <hip/hip_runtime.h>
#include <hip/hip_bf16.h>

#define NN 100000
#define NE 1600000
#define INDIM 48
#define HID 128
#define K2 256
#define BN_EPS 1e-5f

// bucket sort parameters: buckets of 256 dst nodes
#define NBUK 391          // ceil(100000/256)
#define BCAP 5120         // mean 4096, sigma~64 -> 16 sigma headroom
#define CHUNK 8192        // edges per phase-1 block

typedef short s8v __attribute__((ext_vector_type(8)));
typedef float f4v __attribute__((ext_vector_type(4)));

__device__ __forceinline__ unsigned short f2bf(float f) {
    __hip_bfloat16 b = __float2bfloat16(f);
    unsigned short u;
    __builtin_memcpy(&u, &b, 2);
    return u;
}
__device__ __forceinline__ float bf2f(unsigned short u) {
    return __uint_as_float(((unsigned)u) << 16);
}

// ---------------- input projection: pass 1, BN1 column stats ----------------
__global__ __launch_bounds__(256) void k_proj_stats(
    const float* __restrict__ x, const float* __restrict__ W1, const float* __restrict__ b1,
    float* __restrict__ colSum, float* __restrict__ colSq) {
  __shared__ float wT[INDIM][HID];        // 24 KB, transposed: bank-conflict-free
  __shared__ float redS[2][HID], redQ[2][HID];
  int tid = threadIdx.x;
  for (int i = tid; i < HID * INDIM; i += 256) {
    int c = i / INDIM, k = i - c * INDIM;
    wT[k][c] = W1[i];
  }
  __syncthreads();
  int c = tid & (HID - 1);
  int rl = tid >> 7;
  float bb = b1[c];
  float sum = 0.f, sq = 0.f;
  for (int r = blockIdx.x * 2 + rl; r < NN; r += gridDim.x * 2) {
    const float4* xr = (const float4*)(x + (size_t)r * INDIM);  // wave-uniform broadcast loads
    float h = bb;
#pragma unroll
    for (int k4 = 0; k4 < INDIM / 4; ++k4) {
      float4 xv = xr[k4];
      h = fmaf(xv.x, wT[4 * k4 + 0][c], h);
      h = fmaf(xv.y, wT[4 * k4 + 1][c], h);
      h = fmaf(xv.z, wT[4 * k4 + 2][c], h);
      h = fmaf(xv.w, wT[4 * k4 + 3][c], h);
    }
    sum += h;
    sq = fmaf(h, h, sq);
  }
  redS[rl][c] = sum;
  redQ[rl][c] = sq;
  __syncthreads();
  if (rl == 0) {
    atomicAdd(&colSum[c], redS[0][c] + redS[1][c]);
    atomicAdd(&colSq[c], redQ[0][c] + redQ[1][c]);
  }
}

// ---------------- BN finalize: a = g*rsqrt(var+eps), b = be - mu*a ----------------
__global__ void k_bn_final(const float* __restrict__ sum, const float* __restrict__ sq,
                           const float* __restrict__ gamma, const float* __restrict__ beta,
                           float* __restrict__ av, float* __restrict__ bv) {
  int c = threadIdx.x;
  float mu = sum[c] * (1.0f / NN);
  float var = fmaxf(sq[c] * (1.0f / NN) - mu * mu, 0.f);
  float a = gamma[c] * rsqrtf(var + BN_EPS);
  av[c] = a;
  bv[c] = beta[c] - mu * a;
}

// ---------------- input projection: pass 2, recompute h, apply BN1+ReLU ----------------
__global__ __launch_bounds__(256) void k_proj_apply(
    const float* __restrict__ x, const float* __restrict__ W1, const float* __restrict__ b1,
    const float* __restrict__ av, const float* __restrict__ bv,
    float* __restrict__ feat, unsigned short* __restrict__ A) {
  __shared__ float wT[INDIM][HID];
  int tid = threadIdx.x;
  for (int i = tid; i < HID * INDIM; i += 256) {
    int c = i / INDIM, k = i - c * INDIM;
    wT[k][c] = W1[i];
  }
  __syncthreads();
  int c = tid & (HID - 1);
  int rl = tid >> 7;
  float bb1 = b1[c];
  float aa = av[c], bb2 = bv[c];
  for (int r = blockIdx.x * 2 + rl; r < NN; r += gridDim.x * 2) {
    const float4* xr = (const float4*)(x + (size_t)r * INDIM);
    float h = bb1;
#pragma unroll
    for (int k4 = 0; k4 < INDIM / 4; ++k4) {
      float4 xv = xr[k4];
      h = fmaf(xv.x, wT[4 * k4 + 0][c], h);
      h = fmaf(xv.y, wT[4 * k4 + 1][c], h);
      h = fmaf(xv.z, wT[4 * k4 + 2][c], h);
      h = fmaf(xv.w, wT[4 * k4 + 3][c], h);
    }
    float f = fmaxf(fmaf(h, aa, bb2), 0.f);
    feat[(size_t)r * HID + c] = f;                 // output 0 (fp32)
    A[(size_t)r * K2 + HID + c] = f2bf(f);         // bf16 copy -> GEMM A cols 128..255
  }
}

// ---------------- phase 1: LDS-binned bucket scatter of edges ----------------
// Bins edges by dst>>8 into NBUK fixed-capacity bucket arrays. Packed entry:
// src (17 bits) | local_dst (8 bits) << 17. Copy-out is runs of ~21 entries
// per bucket per chunk -> mostly-coalesced writes (vs 105 MB dirty-line
// traffic for the old random 4B CSR scatter).
__global__ __launch_bounds__(256) void k_bucket(const int* __restrict__ ei,
                                                int* __restrict__ bcur,
                                                unsigned int* __restrict__ bbuf) {
  __shared__ int cnt[512];
  __shared__ int sc[2][512];
  __shared__ int ofs[512];
  __shared__ int lcur[512];
  __shared__ int gbase[512];
  __shared__ unsigned int stag[CHUNK];       // 32 KB
  __shared__ unsigned short sbkt[CHUNK];     // 16 KB
  int tid = threadIdx.x;
  int base = blockIdx.x * CHUNK;
  int lim = min(CHUNK, NE - base);
  cnt[tid] = 0;
  cnt[tid + 256] = 0;
  __syncthreads();
  // pass A: per-bucket counts for this chunk
#pragma unroll
  for (int i = 0; i < CHUNK / 256; ++i) {
    int e = i * 256 + tid;
    if (e < lim) {
      int d = ei[NE + base + e];
      d = min(max(d, 0), NN - 1);
      atomicAdd(&cnt[d >> 8], 1);
    }
  }
  __syncthreads();
  // pass B: inclusive scan over 512 (2 elems/thread, Hillis-Steele)
  sc[0][tid] = cnt[tid];
  sc[0][tid + 256] = cnt[tid + 256];
  __syncthreads();
  int pp = 0;
  for (int d = 1; d < 512; d <<= 1) {
    int a0 = sc[pp][tid];
    int a1 = sc[pp][tid + 256];
    if (tid >= d) a0 += sc[pp][tid - d];
    a1 += sc[pp][tid + 256 - d];   // tid+256 >= d always (d <= 256)
    sc[pp ^ 1][tid] = a0;
    sc[pp ^ 1][tid + 256] = a1;
    __syncthreads();
    pp ^= 1;
  }
  ofs[tid] = sc[pp][tid] - cnt[tid];
  ofs[tid + 256] = sc[pp][tid + 256] - cnt[tid + 256];
  lcur[tid] = ofs[tid];
  lcur[tid + 256] = ofs[tid + 256];
  if (tid < NBUK) gbase[tid] = atomicAdd(&bcur[tid], cnt[tid]);
  if (tid + 256 < NBUK) gbase[tid + 256] = atomicAdd(&bcur[tid + 256], cnt[tid + 256]);
  __syncthreads();
  // pass C: scatter packed entries into bucket-ordered LDS staging
#pragma unroll
  for (int i = 0; i < CHUNK / 256; ++i) {
    int e = i * 256 + tid;
    if (e < lim) {
      int s = ei[base + e];
      int d = ei[NE + base + e];
      s = min(max(s, 0), NN - 1);
      d = min(max(d, 0), NN - 1);
      int b = d >> 8;
      int pos = atomicAdd(&lcur[b], 1);
      stag[pos] = (unsigned)s | ((unsigned)(d & 255) << 17);
      sbkt[pos] = (unsigned short)b;
    }
  }
  __syncthreads();
  // pass D: coalesced copy-out (consecutive slots in a bucket -> consecutive global)
  for (int s = tid; s < lim; s += 256) {
    int b = sbkt[s];
    int off = gbase[b] + (s - ofs[b]);
    if (off < BCAP) bbuf[(size_t)b * BCAP + off] = stag[s];
  }
}

// ---------------- phase 2: per-bucket local CSR (in LDS) + mean aggregation ----------------
__global__ __launch_bounds__(512) void k_bucket_agg(const unsigned int* __restrict__ bbuf,
                                                    const int* __restrict__ bcnt,
                                                    unsigned short* Abuf) {
  __shared__ unsigned int lcsr[BCAP];   // 20 KB
  __shared__ int cnt[256], ofs[256], cur[256];
  __shared__ int sc[2][256];
  int tid = threadIdx.x;
  int b = blockIdx.x;
  int m = min(bcnt[b], BCAP);
  int n0 = b << 8;
  int nb = min(256, NN - n0);
  if (tid < 256) cnt[tid] = 0;
  __syncthreads();
  const unsigned int* bp = bbuf + (size_t)b * BCAP;
  for (int s = tid; s < m; s += 512) {
    unsigned p = bp[s];
    atomicAdd(&cnt[(p >> 17) & 255], 1);
  }
  __syncthreads();
  if (tid < 256) sc[0][tid] = cnt[tid];
  __syncthreads();
  int pp = 0;
  for (int d = 1; d < 256; d <<= 1) {
    if (tid < 256) {
      int v = sc[pp][tid];
      if (tid >= d) v += sc[pp][tid - d];
      sc[pp ^ 1][tid] = v;
    }
    __syncthreads();
    pp ^= 1;
  }
  if (tid < 256) {
    int o = sc[pp][tid] - cnt[tid];
    ofs[tid] = o;
    cur[tid] = o;
  }
  __syncthreads();
  for (int s = tid; s < m; s += 512) {
    unsigned p = bp[s];     // L1/L2-hot second read
    int ld = (p >> 17) & 255;
    int pos = atomicAdd(&cur[ld], 1);
    lcsr[pos] = p & 0x1FFFF;
  }
  __syncthreads();
  // aggregate: 16 groups of 32 lanes; each group owns node ln, gathers bf16 feat rows
  int lane = tid & 31;
  int g = tid >> 5;
  for (int ln = g; ln < nb; ln += 16) {
    int deg = cnt[ln], beg = ofs[ln];
    float a0 = 0.f, a1 = 0.f, a2 = 0.f, a3 = 0.f;
    int j = 0;
    for (; j + 1 < deg; j += 2) {
      int s0 = lcsr[beg + j];
      int s1 = lcsr[beg + j + 1];
      ushort4 v0 = *(const ushort4*)(Abuf + (size_t)s0 * K2 + HID + lane * 4);
      ushort4 v1 = *(const ushort4*)(Abuf + (size_t)s1 * K2 + HID + lane * 4);
      a0 += bf2f(v0.x) + bf2f(v1.x);
      a1 += bf2f(v0.y) + bf2f(v1.y);
      a2 += bf2f(v0.z) + bf2f(v1.z);
      a3 += bf2f(v0.w) + bf2f(v1.w);
    }
    if (j < deg) {
      int s0 = lcsr[beg + j];
      ushort4 v0 = *(const ushort4*)(Abuf + (size_t)s0 * K2 + HID + lane * 4);
      a0 += bf2f(v0.x);
      a1 += bf2f(v0.y);
      a2 += bf2f(v0.z);
      a3 += bf2f(v0.w);
    }
    float inv = 1.f / fmaxf((float)deg, 1.f);
    ushort4 o;
    o.x = f2bf(a0 * inv);
    o.y = f2bf(a1 * inv);
    o.z = f2bf(a2 * inv);
    o.w = f2bf(a3 * inv);
    *(ushort4*)(Abuf + (size_t)(n0 + ln) * K2 + lane * 4) = o;
  }
}

// ---------------- bf16 weight prep: Wcat[j][0:128]=Wl[j], [128:256]=Wr[j] ----------------
__global__ __launch_bounds__(256) void k_prep_w(const float* __restrict__ Wl, const float* __restrict__ Wr,
                                                unsigned short* __restrict__ Wcat) {
  int i = blockIdx.x * 256 + threadIdx.x;
  if (i < HID * K2) {
    int j = i >> 8, k = i & (K2 - 1);
    float v = (k < HID) ? Wl[j * HID + k] : Wr[j * HID + (k - HID)];
    Wcat[i] = f2bf(v);
  }
}

// ---------------- MFMA GEMM: sage = A[N,256] @ Wcat[128,256]^T + bl; BN2 stats fused ----------------
#define MT ((NN + 63) / 64)  // 1563 row tiles of 64

__global__ __launch_bounds__(256) void k_gemm(
    const unsigned short* __restrict__ A, const unsigned short* __restrict__ Wcat,
    const float* __restrict__ bl, float* __restrict__ sage,
    float* __restrict__ colSum, float* __restrict__ colSq) {
  __shared__ __align__(16) unsigned short Bsh[64][264];  // 64 cols x 256 k, +8 pad
  __shared__ float redS[4][64], redQ[4][64];
  int tid = threadIdx.x;
  int ch = blockIdx.y;  // column half: cols ch*64 .. ch*64+63
  for (int i = tid; i < 64 * 32; i += 256) {
    int j = i >> 5;
    int kg = (i & 31) << 3;
    *(s8v*)&Bsh[j][kg] = *(const s8v*)(Wcat + ((size_t)(ch * 64 + j)) * K2 + kg);
  }
  __syncthreads();
  int w = tid >> 6, l = tid & 63;
  int m16 = l & 15, q = l >> 4;
  float ssum[4] = {0.f, 0.f, 0.f, 0.f}, ssq[4] = {0.f, 0.f, 0.f, 0.f};
  f4v zero4 = {0.f, 0.f, 0.f, 0.f};
  s8v zero8 = {0, 0, 0, 0, 0, 0, 0, 0};
  for (int tile = blockIdx.x; tile < MT; tile += gridDim.x) {
    int row = tile * 64 + w * 16 + m16;  // A-frag row (m = lane&15)
    bool rv = row < NN;
    f4v acc[4];
#pragma unroll
    for (int nt = 0; nt < 4; ++nt) acc[nt] = zero4;
#pragma unroll
    for (int kt = 0; kt < 8; ++kt) {
      s8v a = zero8;
      if (rv) a = *(const s8v*)(A + (size_t)row * K2 + kt * 32 + q * 8);  // k = quad*8+j
#pragma unroll
      for (int nt = 0; nt < 4; ++nt) {
        s8v bfr = *(const s8v*)(&Bsh[nt * 16 + m16][kt * 32 + q * 8]);  // B[n=lane&15][k]
        acc[nt] = __builtin_amdgcn_mfma_f32_16x16x32_bf16(a, bfr, acc[nt], 0, 0, 0);
      }
    }
    int rbase = tile * 64 + w * 16 + q * 4;  // C row = quad*4 + reg
#pragma unroll
    for (int nt = 0; nt < 4; ++nt) {
      int col = ch * 64 + nt * 16 + m16;  // C col = lane&15
      float bv = bl[col];
#pragma unroll
      for (int r4 = 0; r4 < 4; ++r4) {
        int rr = rbase + r4;
        if (rr < NN) {
          float v = acc[nt][r4] + bv;
          sage[(size_t)rr * HID + col] = v;
          ssum[nt] += v;
          ssq[nt] = fmaf(v, v, ssq[nt]);
        }
      }
    }
  }
  // reduce BN2 stats: lanes {l, l^16, l^32, l^48} share a column
#pragma unroll
  for (int nt = 0; nt < 4; ++nt) {
    float s = ssum[nt], qq = ssq[nt];
    s += __shfl_xor(s, 16);
    s += __shfl_xor(s, 32);
    qq += __shfl_xor(qq, 16);
    qq += __shfl_xor(qq, 32);
    if (q == 0) {
      redS[w][nt * 16 + m16] = s;
      redQ[w][nt * 16 + m16] = qq;
    }
  }
  __syncthreads();
  if (tid < 64) {
    float s = redS[0][tid] + redS[1][tid] + redS[2][tid] + redS[3][tid];
    float qq = redQ[0][tid] + redQ[1][tid] + redQ[2][tid] + redQ[3][tid];
    atomicAdd(&colSum[ch * 64 + tid], s);
    atomicAdd(&colSq[ch * 64 + tid], qq);
  }
}

// ---------------- BN2 apply, in-place on d_out second half ----------------
__global__ __launch_bounds__(256) void k_bn_apply(float* __restrict__ sage,
                                                  const float* __restrict__ av,
                                                  const float* __restrict__ bv) {
  int i = blockIdx.x * 256 + threadIdx.x;  // float4 index
  if (i < NN * HID / 4) {
    float4 s = ((const float4*)sage)[i];
    int c = (i * 4) & (HID - 1);
    float4 a = *(const float4*)(av + c);
    float4 b = *(const float4*)(bv + c);
    float4 o;
    o.x = fmaf(s.x, a.x, b.x);
    o.y = fmaf(s.y, a.y, b.y);
    o.z = fmaf(s.z, a.z, b.z);
    o.w = fmaf(s.w, a.w, b.w);
    ((float4*)sage)[i] = o;
  }
}

extern "C" void kernel_launch(void* const* d_in, const int* in_sizes, int n_in,
                              void* d_out, int out_size, void* d_ws, size_t ws_size,
                              hipStream_t stream) {
  const float* x   = (const float*)d_in[0];
  const int*   ei  = (const int*)d_in[1];
  const float* W1  = (const float*)d_in[2];
  const float* b1  = (const float*)d_in[3];
  const float* g1  = (const float*)d_in[4];
  const float* be1 = (const float*)d_in[5];
  const float* Wl  = (const float*)d_in[6];
  const float* bl  = (const float*)d_in[7];
  const float* Wr  = (const float*)d_in[8];
  const float* g2  = (const float*)d_in[9];
  const float* be2 = (const float*)d_in[10];

  float* feat_out = (float*)d_out;                      // output 0: feat [NN][HID] fp32
  float* sage     = (float*)d_out + (size_t)NN * HID;   // output 1 region (sage, BN2'd in place)

  size_t off = 0;
  auto alloc = [&](size_t bytes) -> void* {
    void* p = (char*)d_ws + off;
    off += (bytes + 255) & ~(size_t)255;
    return p;
  };
  unsigned short* Abuf = (unsigned short*)alloc((size_t)NN * K2 * 2);  // [NN][256] bf16: agg|feat
  unsigned int*   bbuf = (unsigned int*)alloc((size_t)NBUK * BCAP * 4);
  int*            bcur = (int*)alloc((size_t)NBUK * 4);
  float*          stats = (float*)alloc(8 * HID * 4);
  float* colSum1 = stats;
  float* colSq1  = stats + HID;
  float* colSum2 = stats + 2 * HID;
  float* colSq2  = stats + 3 * HID;
  float* a1v     = stats + 4 * HID;
  float* b1v     = stats + 5 * HID;
  float* a2v     = stats + 6 * HID;
  float* b2v     = stats + 7 * HID;
  unsigned short* Wcat = (unsigned short*)alloc((size_t)HID * K2 * 2);

  hipMemsetAsync(bcur, 0, (size_t)NBUK * 4, stream);
  hipMemsetAsync(stats, 0, 4 * HID * 4, stream);

  k_prep_w<<<(HID * K2 + 255) / 256, 256, 0, stream>>>(Wl, Wr, Wcat);
  k_bucket<<<(NE + CHUNK - 1) / CHUNK, 256, 0, stream>>>(ei, bcur, bbuf);
  k_proj_stats<<<1024, 256, 0, stream>>>(x, W1, b1, colSum1, colSq1);
  k_bn_final<<<1, HID, 0, stream>>>(colSum1, colSq1, g1, be1, a1v, b1v);
  k_proj_apply<<<1024, 256, 0, stream>>>(x, W1, b1, a1v, b1v, feat_out, Abuf);
  k_bucket_agg<<<NBUK, 512, 0, stream>>>(bbuf, bcur, Abuf);
  k_gemm<<<dim3(512, 2), 256, 0, stream>>>(Abuf, Wcat, bl, sage, colSum2, colSq2);
  k_bn_final<<<1, HID, 0, stream>>>(colSum2, colSq2, g2, be2, a2v, b2v);
  k_bn_apply<<<(NN * HID / 4 + 255) / 256, 256, 0, stream>>>(sage, a2v, b2v);
}

// Round 3
// 349.974 us; speedup vs baseline: 1.8574x; 1.3527x over previous
//
#include <hip/hip_runtime.h>
#include <hip/hip_bf16.h>

#define NN 100000
#define NE 1600000
#define INDIM 48
#define HID 128
#define K2 256
#define KP 64            // padded K for input projection
#define BN_EPS 1e-5f

// bucket sort parameters: buckets of 256 dst nodes
#define NBUK 391          // ceil(100000/256)
#define BCAP 5120         // mean 4096, sigma~64 -> 16 sigma headroom
#define CHUNK 8192        // edges per phase-1 block

#define MT ((NN + 63) / 64)  // 1563 row tiles of 64

typedef short s8v __attribute__((ext_vector_type(8)));
typedef float f4v __attribute__((ext_vector_type(4)));

__device__ __forceinline__ unsigned short f2bf(float f) {
    __hip_bfloat16 b = __float2bfloat16(f);
    unsigned short u;
    __builtin_memcpy(&u, &b, 2);
    return u;
}
__device__ __forceinline__ float bf2f(unsigned short u) {
    return __uint_as_float(((unsigned)u) << 16);
}

// ---------------- weight prep ----------------
__global__ __launch_bounds__(256) void k_prep_w(const float* __restrict__ Wl, const float* __restrict__ Wr,
                                                unsigned short* __restrict__ Wcat) {
  int i = blockIdx.x * 256 + threadIdx.x;
  if (i < HID * K2) {
    int j = i >> 8, k = i & (K2 - 1);
    float v = (k < HID) ? Wl[j * HID + k] : Wr[j * HID + (k - HID)];
    Wcat[i] = f2bf(v);
  }
}

__global__ __launch_bounds__(256) void k_prep_w1(const float* __restrict__ W1,
                                                 unsigned short* __restrict__ W1b) {
  int i = blockIdx.x * 256 + threadIdx.x;
  if (i < HID * KP) {
    int j = i >> 6, k = i & (KP - 1);
    W1b[i] = (k < INDIM) ? f2bf(W1[j * INDIM + k]) : (unsigned short)0;
  }
}

// ---------------- x cast: fp32 [NN][48] -> bf16 [NN][64] zero-padded ----------------
__global__ __launch_bounds__(256) void k_xcast(const float* __restrict__ x,
                                               unsigned short* __restrict__ xbf) {
  int i = blockIdx.x * 256 + threadIdx.x;  // quad index: NN*16
  if (i >= NN * 16) return;
  int r = i >> 4, c4 = (i & 15) << 2;
  ushort4 o = {0, 0, 0, 0};
  if (c4 < INDIM) {
    float4 v = *(const float4*)(x + (size_t)r * INDIM + c4);
    o.x = f2bf(v.x);
    o.y = f2bf(v.y);
    o.z = f2bf(v.z);
    o.w = f2bf(v.w);
  }
  *(ushort4*)(xbf + (size_t)r * KP + c4) = o;
}

// ---------------- input projection via MFMA: h = xbf @ W1b^T + b1 ----------------
// h written fp32 into the feat output region; BN1 column stats fused.
__global__ __launch_bounds__(256) void k_proj_gemm(
    const unsigned short* __restrict__ xbf, const unsigned short* __restrict__ W1b,
    const float* __restrict__ b1, float* __restrict__ hout,
    float* __restrict__ colSum, float* __restrict__ colSq) {
  __shared__ __align__(16) unsigned short Bsh[HID][KP + 8];  // 18.4 KB
  __shared__ float redS[4][HID], redQ[4][HID];
  int tid = threadIdx.x;
  for (int i = tid; i < HID * (KP / 8); i += 256) {
    int j = i >> 3, kg = (i & 7) << 3;
    *(s8v*)&Bsh[j][kg] = *(const s8v*)(W1b + (size_t)j * KP + kg);
  }
  __syncthreads();
  int w = tid >> 6, l = tid & 63;
  int m16 = l & 15, q = l >> 4;
  float bcol[8];
#pragma unroll
  for (int nt = 0; nt < 8; ++nt) bcol[nt] = b1[nt * 16 + m16];
  float ssum[8], ssq[8];
#pragma unroll
  for (int nt = 0; nt < 8; ++nt) { ssum[nt] = 0.f; ssq[nt] = 0.f; }
  f4v zero4 = {0.f, 0.f, 0.f, 0.f};
  s8v zero8 = {0, 0, 0, 0, 0, 0, 0, 0};
  for (int tile = blockIdx.x; tile < MT; tile += gridDim.x) {
    int row = tile * 64 + w * 16 + m16;
    bool rv = row < NN;
    f4v acc[8];
#pragma unroll
    for (int nt = 0; nt < 8; ++nt) acc[nt] = zero4;
#pragma unroll
    for (int kt = 0; kt < 2; ++kt) {
      s8v a = zero8;
      if (rv) a = *(const s8v*)(xbf + (size_t)row * KP + kt * 32 + q * 8);
#pragma unroll
      for (int nt = 0; nt < 8; ++nt) {
        s8v b = *(const s8v*)(&Bsh[nt * 16 + m16][kt * 32 + q * 8]);
        acc[nt] = __builtin_amdgcn_mfma_f32_16x16x32_bf16(a, b, acc[nt], 0, 0, 0);
      }
    }
    int rbase = tile * 64 + w * 16 + q * 4;
#pragma unroll
    for (int nt = 0; nt < 8; ++nt) {
      int col = nt * 16 + m16;
#pragma unroll
      for (int r4 = 0; r4 < 4; ++r4) {
        int rr = rbase + r4;
        if (rr < NN) {
          float v = acc[nt][r4] + bcol[nt];
          hout[(size_t)rr * HID + col] = v;
          ssum[nt] += v;
          ssq[nt] = fmaf(v, v, ssq[nt]);
        }
      }
    }
  }
#pragma unroll
  for (int nt = 0; nt < 8; ++nt) {
    float s = ssum[nt], qq = ssq[nt];
    s += __shfl_xor(s, 16);
    s += __shfl_xor(s, 32);
    qq += __shfl_xor(qq, 16);
    qq += __shfl_xor(qq, 32);
    if (q == 0) {
      redS[w][nt * 16 + m16] = s;
      redQ[w][nt * 16 + m16] = qq;
    }
  }
  __syncthreads();
  if (tid < HID) {
    float s = redS[0][tid] + redS[1][tid] + redS[2][tid] + redS[3][tid];
    float qq = redQ[0][tid] + redQ[1][tid] + redQ[2][tid] + redQ[3][tid];
    atomicAdd(&colSum[tid], s);
    atomicAdd(&colSq[tid], qq);
  }
}

// ---------------- BN finalize: a = g*rsqrt(var+eps), b = be - mu*a ----------------
__global__ void k_bn_final(const float* __restrict__ sum, const float* __restrict__ sq,
                           const float* __restrict__ gamma, const float* __restrict__ beta,
                           float* __restrict__ av, float* __restrict__ bv) {
  int c = threadIdx.x;
  float mu = sum[c] * (1.0f / NN);
  float var = fmaxf(sq[c] * (1.0f / NN) - mu * mu, 0.f);
  float a = gamma[c] * rsqrtf(var + BN_EPS);
  av[c] = a;
  bv[c] = beta[c] - mu * a;
}

// ---------------- BN1+ReLU apply: feat = relu(a*h+b) in place; bf16 copy -> Abuf ----------------
__global__ __launch_bounds__(256) void k_apply(float* __restrict__ feat,
                                               const float* __restrict__ av,
                                               const float* __restrict__ bv,
                                               unsigned short* __restrict__ A) {
  int i = blockIdx.x * 256 + threadIdx.x;  // quad index: NN*32
  if (i >= NN * 32) return;
  int r = i >> 5, c4 = (i & 31) << 2;
  float4 h = *(const float4*)(feat + (size_t)r * HID + c4);
  float4 a = *(const float4*)(av + c4);
  float4 b = *(const float4*)(bv + c4);
  float4 f;
  f.x = fmaxf(fmaf(h.x, a.x, b.x), 0.f);
  f.y = fmaxf(fmaf(h.y, a.y, b.y), 0.f);
  f.z = fmaxf(fmaf(h.z, a.z, b.z), 0.f);
  f.w = fmaxf(fmaf(h.w, a.w, b.w), 0.f);
  *(float4*)(feat + (size_t)r * HID + c4) = f;
  ushort4 o;
  o.x = f2bf(f.x);
  o.y = f2bf(f.y);
  o.z = f2bf(f.z);
  o.w = f2bf(f.w);
  *(ushort4*)(A + (size_t)r * K2 + HID + c4) = o;
}

// ---------------- phase 1: LDS-binned bucket scatter of edges ----------------
__global__ __launch_bounds__(256) void k_bucket(const int* __restrict__ ei,
                                                int* __restrict__ bcur,
                                                unsigned int* __restrict__ bbuf) {
  __shared__ int cnt[512];
  __shared__ int sc[2][512];
  __shared__ int ofs[512];
  __shared__ int lcur[512];
  __shared__ int gbase[512];
  __shared__ unsigned int stag[CHUNK];       // 32 KB
  __shared__ unsigned short sbkt[CHUNK];     // 16 KB
  int tid = threadIdx.x;
  int base = blockIdx.x * CHUNK;
  int lim = min(CHUNK, NE - base);
  cnt[tid] = 0;
  cnt[tid + 256] = 0;
  __syncthreads();
#pragma unroll
  for (int i = 0; i < CHUNK / 256; ++i) {
    int e = i * 256 + tid;
    if (e < lim) {
      int d = ei[NE + base + e];
      d = min(max(d, 0), NN - 1);
      atomicAdd(&cnt[d >> 8], 1);
    }
  }
  __syncthreads();
  sc[0][tid] = cnt[tid];
  sc[0][tid + 256] = cnt[tid + 256];
  __syncthreads();
  int pp = 0;
  for (int d = 1; d < 512; d <<= 1) {
    int a0 = sc[pp][tid];
    int a1 = sc[pp][tid + 256];
    if (tid >= d) a0 += sc[pp][tid - d];
    a1 += sc[pp][tid + 256 - d];
    sc[pp ^ 1][tid] = a0;
    sc[pp ^ 1][tid + 256] = a1;
    __syncthreads();
    pp ^= 1;
  }
  ofs[tid] = sc[pp][tid] - cnt[tid];
  ofs[tid + 256] = sc[pp][tid + 256] - cnt[tid + 256];
  lcur[tid] = ofs[tid];
  lcur[tid + 256] = ofs[tid + 256];
  if (tid < NBUK) gbase[tid] = atomicAdd(&bcur[tid], cnt[tid]);
  if (tid + 256 < NBUK) gbase[tid + 256] = atomicAdd(&bcur[tid + 256], cnt[tid + 256]);
  __syncthreads();
#pragma unroll
  for (int i = 0; i < CHUNK / 256; ++i) {
    int e = i * 256 + tid;
    if (e < lim) {
      int s = ei[base + e];
      int d = ei[NE + base + e];
      s = min(max(s, 0), NN - 1);
      d = min(max(d, 0), NN - 1);
      int b = d >> 8;
      int pos = atomicAdd(&lcur[b], 1);
      stag[pos] = (unsigned)s | ((unsigned)(d & 255) << 17);
      sbkt[pos] = (unsigned short)b;
    }
  }
  __syncthreads();
  for (int s = tid; s < lim; s += 256) {
    int b = sbkt[s];
    int off = gbase[b] + (s - ofs[b]);
    if (off < BCAP) bbuf[(size_t)b * BCAP + off] = stag[s];
  }
}

// ---------------- phase 2: per-bucket local CSR (in LDS) + mean aggregation ----------------
__global__ __launch_bounds__(512) void k_bucket_agg(const unsigned int* __restrict__ bbuf,
                                                    const int* __restrict__ bcnt,
                                                    unsigned short* Abuf) {
  __shared__ unsigned int lcsr[BCAP];   // 20 KB
  __shared__ int cnt[256], ofs[256], cur[256];
  __shared__ int sc[2][256];
  int tid = threadIdx.x;
  int b = blockIdx.x;
  int m = min(bcnt[b], BCAP);
  int n0 = b << 8;
  int nb = min(256, NN - n0);
  if (tid < 256) cnt[tid] = 0;
  __syncthreads();
  const unsigned int* bp = bbuf + (size_t)b * BCAP;
  for (int s = tid; s < m; s += 512) {
    unsigned p = bp[s];
    atomicAdd(&cnt[(p >> 17) & 255], 1);
  }
  __syncthreads();
  if (tid < 256) sc[0][tid] = cnt[tid];
  __syncthreads();
  int pp = 0;
  for (int d = 1; d < 256; d <<= 1) {
    if (tid < 256) {
      int v = sc[pp][tid];
      if (tid >= d) v += sc[pp][tid - d];
      sc[pp ^ 1][tid] = v;
    }
    __syncthreads();
    pp ^= 1;
  }
  if (tid < 256) {
    int o = sc[pp][tid] - cnt[tid];
    ofs[tid] = o;
    cur[tid] = o;
  }
  __syncthreads();
  for (int s = tid; s < m; s += 512) {
    unsigned p = bp[s];
    int ld = (p >> 17) & 255;
    int pos = atomicAdd(&cur[ld], 1);
    lcsr[pos] = p & 0x1FFFF;
  }
  __syncthreads();
  int lane = tid & 31;
  int g = tid >> 5;
  for (int ln = g; ln < nb; ln += 16) {
    int deg = cnt[ln], beg = ofs[ln];
    float a0 = 0.f, a1 = 0.f, a2 = 0.f, a3 = 0.f;
    int j = 0;
    for (; j + 1 < deg; j += 2) {
      int s0 = lcsr[beg + j];
      int s1 = lcsr[beg + j + 1];
      ushort4 v0 = *(const ushort4*)(Abuf + (size_t)s0 * K2 + HID + lane * 4);
      ushort4 v1 = *(const ushort4*)(Abuf + (size_t)s1 * K2 + HID + lane * 4);
      a0 += bf2f(v0.x) + bf2f(v1.x);
      a1 += bf2f(v0.y) + bf2f(v1.y);
      a2 += bf2f(v0.z) + bf2f(v1.z);
      a3 += bf2f(v0.w) + bf2f(v1.w);
    }
    if (j < deg) {
      int s0 = lcsr[beg + j];
      ushort4 v0 = *(const ushort4*)(Abuf + (size_t)s0 * K2 + HID + lane * 4);
      a0 += bf2f(v0.x);
      a1 += bf2f(v0.y);
      a2 += bf2f(v0.z);
      a3 += bf2f(v0.w);
    }
    float inv = 1.f / fmaxf((float)deg, 1.f);
    ushort4 o;
    o.x = f2bf(a0 * inv);
    o.y = f2bf(a1 * inv);
    o.z = f2bf(a2 * inv);
    o.w = f2bf(a3 * inv);
    *(ushort4*)(Abuf + (size_t)(n0 + ln) * K2 + lane * 4) = o;
  }
}

// ---------------- MFMA GEMM: sage = A[N,256] @ Wcat[128,256]^T + bl; BN2 stats fused ----------------
__global__ __launch_bounds__(256) void k_gemm(
    const unsigned short* __restrict__ A, const unsigned short* __restrict__ Wcat,
    const float* __restrict__ bl, float* __restrict__ sage,
    float* __restrict__ colSum, float* __restrict__ colSq) {
  __shared__ __align__(16) unsigned short Bsh[64][264];  // 64 cols x 256 k, +8 pad
  __shared__ float redS[4][64], redQ[4][64];
  int tid = threadIdx.x;
  int ch = blockIdx.y;  // column half: cols ch*64 .. ch*64+63
  for (int i = tid; i < 64 * 32; i += 256) {
    int j = i >> 5;
    int kg = (i & 31) << 3;
    *(s8v*)&Bsh[j][kg] = *(const s8v*)(Wcat + ((size_t)(ch * 64 + j)) * K2 + kg);
  }
  __syncthreads();
  int w = tid >> 6, l = tid & 63;
  int m16 = l & 15, q = l >> 4;
  float ssum[4] = {0.f, 0.f, 0.f, 0.f}, ssq[4] = {0.f, 0.f, 0.f, 0.f};
  f4v zero4 = {0.f, 0.f, 0.f, 0.f};
  s8v zero8 = {0, 0, 0, 0, 0, 0, 0, 0};
  for (int tile = blockIdx.x; tile < MT; tile += gridDim.x) {
    int row = tile * 64 + w * 16 + m16;
    bool rv = row < NN;
    f4v acc[4];
#pragma unroll
    for (int nt = 0; nt < 4; ++nt) acc[nt] = zero4;
#pragma unroll
    for (int kt = 0; kt < 8; ++kt) {
      s8v a = zero8;
      if (rv) a = *(const s8v*)(A + (size_t)row * K2 + kt * 32 + q * 8);
#pragma unroll
      for (int nt = 0; nt < 4; ++nt) {
        s8v bfr = *(const s8v*)(&Bsh[nt * 16 + m16][kt * 32 + q * 8]);
        acc[nt] = __builtin_amdgcn_mfma_f32_16x16x32_bf16(a, bfr, acc[nt], 0, 0, 0);
      }
    }
    int rbase = tile * 64 + w * 16 + q * 4;
#pragma unroll
    for (int nt = 0; nt < 4; ++nt) {
      int col = ch * 64 + nt * 16 + m16;
      float bv = bl[col];
#pragma unroll
      for (int r4 = 0; r4 < 4; ++r4) {
        int rr = rbase + r4;
        if (rr < NN) {
          float v = acc[nt][r4] + bv;
          sage[(size_t)rr * HID + col] = v;
          ssum[nt] += v;
          ssq[nt] = fmaf(v, v, ssq[nt]);
        }
      }
    }
  }
#pragma unroll
  for (int nt = 0; nt < 4; ++nt) {
    float s = ssum[nt], qq = ssq[nt];
    s += __shfl_xor(s, 16);
    s += __shfl_xor(s, 32);
    qq += __shfl_xor(qq, 16);
    qq += __shfl_xor(qq, 32);
    if (q == 0) {
      redS[w][nt * 16 + m16] = s;
      redQ[w][nt * 16 + m16] = qq;
    }
  }
  __syncthreads();
  if (tid < 64) {
    float s = redS[0][tid] + redS[1][tid] + redS[2][tid] + redS[3][tid];
    float qq = redQ[0][tid] + redQ[1][tid] + redQ[2][tid] + redQ[3][tid];
    atomicAdd(&colSum[ch * 64 + tid], s);
    atomicAdd(&colSq[ch * 64 + tid], qq);
  }
}

// ---------------- BN2 apply, in-place on d_out second half ----------------
__global__ __launch_bounds__(256) void k_bn_apply(float* __restrict__ sage,
                                                  const float* __restrict__ av,
                                                  const float* __restrict__ bv) {
  int i = blockIdx.x * 256 + threadIdx.x;  // float4 index
  if (i < NN * HID / 4) {
    float4 s = ((const float4*)sage)[i];
    int c = (i * 4) & (HID - 1);
    float4 a = *(const float4*)(av + c);
    float4 b = *(const float4*)(bv + c);
    float4 o;
    o.x = fmaf(s.x, a.x, b.x);
    o.y = fmaf(s.y, a.y, b.y);
    o.z = fmaf(s.z, a.z, b.z);
    o.w = fmaf(s.w, a.w, b.w);
    ((float4*)sage)[i] = o;
  }
}

extern "C" void kernel_launch(void* const* d_in, const int* in_sizes, int n_in,
                              void* d_out, int out_size, void* d_ws, size_t ws_size,
                              hipStream_t stream) {
  const float* x   = (const float*)d_in[0];
  const int*   ei  = (const int*)d_in[1];
  const float* W1  = (const float*)d_in[2];
  const float* b1  = (const float*)d_in[3];
  const float* g1  = (const float*)d_in[4];
  const float* be1 = (const float*)d_in[5];
  const float* Wl  = (const float*)d_in[6];
  const float* bl  = (const float*)d_in[7];
  const float* Wr  = (const float*)d_in[8];
  const float* g2  = (const float*)d_in[9];
  const float* be2 = (const float*)d_in[10];

  float* feat_out = (float*)d_out;                      // output 0: h then feat (in place)
  float* sage     = (float*)d_out + (size_t)NN * HID;   // output 1 region (sage, BN2'd in place)

  size_t off = 0;
  auto alloc = [&](size_t bytes) -> void* {
    void* p = (char*)d_ws + off;
    off += (bytes + 255) & ~(size_t)255;
    return p;
  };
  unsigned short* Abuf = (unsigned short*)alloc((size_t)NN * K2 * 2);  // [NN][256] bf16: agg|feat
  unsigned int*   bbuf = (unsigned int*)alloc((size_t)NBUK * BCAP * 4);
  int*            bcur = (int*)alloc((size_t)NBUK * 4);
  float*          stats = (float*)alloc(8 * HID * 4);
  float* colSum1 = stats;
  float* colSq1  = stats + HID;
  float* colSum2 = stats + 2 * HID;
  float* colSq2  = stats + 3 * HID;
  float* a1v     = stats + 4 * HID;
  float* b1v     = stats + 5 * HID;
  float* a2v     = stats + 6 * HID;
  float* b2v     = stats + 7 * HID;
  unsigned short* Wcat = (unsigned short*)alloc((size_t)HID * K2 * 2);
  unsigned short* W1b  = (unsigned short*)alloc((size_t)HID * KP * 2);
  unsigned short* xbf  = (unsigned short*)alloc((size_t)NN * KP * 2);

  hipMemsetAsync(bcur, 0, (size_t)NBUK * 4, stream);
  hipMemsetAsync(stats, 0, 4 * HID * 4, stream);

  k_prep_w<<<(HID * K2 + 255) / 256, 256, 0, stream>>>(Wl, Wr, Wcat);
  k_prep_w1<<<(HID * KP + 255) / 256, 256, 0, stream>>>(W1, W1b);
  k_xcast<<<(NN * 16 + 255) / 256, 256, 0, stream>>>(x, xbf);
  k_bucket<<<(NE + CHUNK - 1) / CHUNK, 256, 0, stream>>>(ei, bcur, bbuf);
  k_proj_gemm<<<512, 256, 0, stream>>>(xbf, W1b, b1, feat_out, colSum1, colSq1);
  k_bn_final<<<1, HID, 0, stream>>>(colSum1, colSq1, g1, be1, a1v, b1v);
  k_apply<<<(NN * 32 + 255) / 256, 256, 0, stream>>>(feat_out, a1v, b1v, Abuf);
  k_bucket_agg<<<NBUK, 512, 0, stream>>>(bbuf, bcur, Abuf);
  k_gemm<<<dim3(512, 2), 256, 0, stream>>>(Abuf, Wcat, bl, sage, colSum2, colSq2);
  k_bn_final<<<1, HID, 0, stream>>>(colSum2, colSq2, g2, be2, a2v, b2v);
  k_bn_apply<<<(NN * HID / 4 + 255) / 256, 256, 0, stream>>>(sage, a2v, b2v);
}

// Round 4
// 326.426 us; speedup vs baseline: 1.9914x; 1.0721x over previous
//
#include <hip/hip_runtime.h>
#include <hip/hip_bf16.h>

#define NN 100000
#define NE 1600000
#define INDIM 48
#define HID 128
#define K2 256
#define KP 64            // padded K for input projection
#define BN_EPS 1e-5f

// bucket sort parameters: buckets of 128 dst nodes
#define NBUK 782          // ceil(100000/128)
#define BCAP 2816         // mean 2046, sigma~45 -> +17 sigma headroom
#define CHUNK 8192        // edges per phase-1 block

#define MT ((NN + 63) / 64)  // 1563 row tiles of 64

typedef short s8v __attribute__((ext_vector_type(8)));
typedef float f4v __attribute__((ext_vector_type(4)));

__device__ __forceinline__ unsigned short f2bf(float f) {
    __hip_bfloat16 b = __float2bfloat16(f);
    unsigned short u;
    __builtin_memcpy(&u, &b, 2);
    return u;
}
__device__ __forceinline__ float bf2f(unsigned short u) {
    return __uint_as_float(((unsigned)u) << 16);
}
__device__ __forceinline__ float bflo(unsigned u) { return __uint_as_float(u << 16); }
__device__ __forceinline__ float bfhi(unsigned u) { return __uint_as_float(u & 0xffff0000u); }
__device__ __forceinline__ unsigned packbf(float lo, float hi) {
    return (unsigned)f2bf(lo) | ((unsigned)f2bf(hi) << 16);
}

// ---------------- fused prep: weights->bf16, zero bcur & stats ----------------
__global__ __launch_bounds__(256) void k_prep(const float* __restrict__ Wl, const float* __restrict__ Wr,
                                              const float* __restrict__ W1,
                                              unsigned short* __restrict__ Wcat,
                                              unsigned short* __restrict__ W1b,
                                              int* __restrict__ bcur, float* __restrict__ stats) {
  int i = blockIdx.x * 256 + threadIdx.x;
  if (i < HID * K2) {  // Wcat
    int j = i >> 8, k = i & (K2 - 1);
    float v = (k < HID) ? Wl[j * HID + k] : Wr[j * HID + (k - HID)];
    Wcat[i] = f2bf(v);
  }
  int i2 = i - HID * K2;
  if (i2 >= 0 && i2 < HID * KP) {  // W1b (zero-padded K 48->64)
    int j = i2 >> 6, k = i2 & (KP - 1);
    W1b[i2] = (k < INDIM) ? f2bf(W1[j * INDIM + k]) : (unsigned short)0;
  }
  int i3 = i2 - HID * KP;
  if (i3 >= 0 && i3 < NBUK) bcur[i3] = 0;
  int i4 = i3 - NBUK;
  if (i4 >= 0 && i4 < 4 * HID) stats[i4] = 0.f;
}

// ---------------- x cast: fp32 [NN][48] -> bf16 [NN][64] zero-padded ----------------
__global__ __launch_bounds__(256) void k_xcast(const float* __restrict__ x,
                                               unsigned short* __restrict__ xbf) {
  int i = blockIdx.x * 256 + threadIdx.x;  // quad index: NN*16
  if (i >= NN * 16) return;
  int r = i >> 4, c4 = (i & 15) << 2;
  ushort4 o = {0, 0, 0, 0};
  if (c4 < INDIM) {
    float4 v = *(const float4*)(x + (size_t)r * INDIM + c4);
    o.x = f2bf(v.x);
    o.y = f2bf(v.y);
    o.z = f2bf(v.z);
    o.w = f2bf(v.w);
  }
  *(ushort4*)(xbf + (size_t)r * KP + c4) = o;
}

// ---------------- input projection via MFMA: h = xbf @ W1b^T + b1 ----------------
// h written bf16 into Abuf cols 128..255; BN1 column stats (fp32) fused.
__global__ __launch_bounds__(256) void k_proj_gemm(
    const unsigned short* __restrict__ xbf, const unsigned short* __restrict__ W1b,
    const float* __restrict__ b1, unsigned short* __restrict__ Abuf,
    float* __restrict__ colSum, float* __restrict__ colSq) {
  __shared__ __align__(16) unsigned short Bsh[HID][KP + 8];  // 18.4 KB
  __shared__ float redS[4][HID], redQ[4][HID];
  int tid = threadIdx.x;
  for (int i = tid; i < HID * (KP / 8); i += 256) {
    int j = i >> 3, kg = (i & 7) << 3;
    *(s8v*)&Bsh[j][kg] = *(const s8v*)(W1b + (size_t)j * KP + kg);
  }
  __syncthreads();
  int w = tid >> 6, l = tid & 63;
  int m16 = l & 15, q = l >> 4;
  float bcol[8];
#pragma unroll
  for (int nt = 0; nt < 8; ++nt) bcol[nt] = b1[nt * 16 + m16];
  float ssum[8], ssq[8];
#pragma unroll
  for (int nt = 0; nt < 8; ++nt) { ssum[nt] = 0.f; ssq[nt] = 0.f; }
  f4v zero4 = {0.f, 0.f, 0.f, 0.f};
  s8v zero8 = {0, 0, 0, 0, 0, 0, 0, 0};
  for (int tile = blockIdx.x; tile < MT; tile += gridDim.x) {
    int row = tile * 64 + w * 16 + m16;
    bool rv = row < NN;
    f4v acc[8];
#pragma unroll
    for (int nt = 0; nt < 8; ++nt) acc[nt] = zero4;
#pragma unroll
    for (int kt = 0; kt < 2; ++kt) {
      s8v a = zero8;
      if (rv) a = *(const s8v*)(xbf + (size_t)row * KP + kt * 32 + q * 8);
#pragma unroll
      for (int nt = 0; nt < 8; ++nt) {
        s8v b = *(const s8v*)(&Bsh[nt * 16 + m16][kt * 32 + q * 8]);
        acc[nt] = __builtin_amdgcn_mfma_f32_16x16x32_bf16(a, b, acc[nt], 0, 0, 0);
      }
    }
    int rbase = tile * 64 + w * 16 + q * 4;
#pragma unroll
    for (int nt = 0; nt < 8; ++nt) {
      int col = nt * 16 + m16;
#pragma unroll
      for (int r4 = 0; r4 < 4; ++r4) {
        int rr = rbase + r4;
        if (rr < NN) {
          float v = acc[nt][r4] + bcol[nt];
          Abuf[(size_t)rr * K2 + HID + col] = f2bf(v);
          ssum[nt] += v;
          ssq[nt] = fmaf(v, v, ssq[nt]);
        }
      }
    }
  }
#pragma unroll
  for (int nt = 0; nt < 8; ++nt) {
    float s = ssum[nt], qq = ssq[nt];
    s += __shfl_xor(s, 16);
    s += __shfl_xor(s, 32);
    qq += __shfl_xor(qq, 16);
    qq += __shfl_xor(qq, 32);
    if (q == 0) {
      redS[w][nt * 16 + m16] = s;
      redQ[w][nt * 16 + m16] = qq;
    }
  }
  __syncthreads();
  if (tid < HID) {
    float s = redS[0][tid] + redS[1][tid] + redS[2][tid] + redS[3][tid];
    float qq = redQ[0][tid] + redQ[1][tid] + redQ[2][tid] + redQ[3][tid];
    atomicAdd(&colSum[tid], s);
    atomicAdd(&colSq[tid], qq);
  }
}

// ---------------- BN finalize: a = g*rsqrt(var+eps), b = be - mu*a ----------------
__global__ void k_bn_final(const float* __restrict__ sum, const float* __restrict__ sq,
                           const float* __restrict__ gamma, const float* __restrict__ beta,
                           float* __restrict__ av, float* __restrict__ bv) {
  int c = threadIdx.x;
  float mu = sum[c] * (1.0f / NN);
  float var = fmaxf(sq[c] * (1.0f / NN) - mu * mu, 0.f);
  float a = gamma[c] * rsqrtf(var + BN_EPS);
  av[c] = a;
  bv[c] = beta[c] - mu * a;
}

// ---------------- BN1+ReLU apply: read bf16 h from Abuf, write fp32 feat + bf16 feat ----------------
__global__ __launch_bounds__(256) void k_apply(float* __restrict__ feat,
                                               const float* __restrict__ av,
                                               const float* __restrict__ bv,
                                               unsigned short* __restrict__ A) {
  int i = blockIdx.x * 256 + threadIdx.x;  // oct index: NN*16
  if (i >= NN * 16) return;
  int r = i >> 4, c8 = (i & 15) << 3;
  unsigned short* ap = A + (size_t)r * K2 + HID + c8;
  uint4 hv = *(const uint4*)ap;
  float4 a0 = *(const float4*)(av + c8);
  float4 a1 = *(const float4*)(av + c8 + 4);
  float4 b0 = *(const float4*)(bv + c8);
  float4 b1 = *(const float4*)(bv + c8 + 4);
  float f0 = fmaxf(fmaf(bflo(hv.x), a0.x, b0.x), 0.f);
  float f1 = fmaxf(fmaf(bfhi(hv.x), a0.y, b0.y), 0.f);
  float f2 = fmaxf(fmaf(bflo(hv.y), a0.z, b0.z), 0.f);
  float f3 = fmaxf(fmaf(bfhi(hv.y), a0.w, b0.w), 0.f);
  float f4 = fmaxf(fmaf(bflo(hv.z), a1.x, b1.x), 0.f);
  float f5 = fmaxf(fmaf(bfhi(hv.z), a1.y, b1.y), 0.f);
  float f6 = fmaxf(fmaf(bflo(hv.w), a1.z, b1.z), 0.f);
  float f7 = fmaxf(fmaf(bfhi(hv.w), a1.w, b1.w), 0.f);
  float4 o0 = {f0, f1, f2, f3}, o1 = {f4, f5, f6, f7};
  *(float4*)(feat + (size_t)r * HID + c8) = o0;
  *(float4*)(feat + (size_t)r * HID + c8 + 4) = o1;
  uint4 ob;
  ob.x = packbf(f0, f1);
  ob.y = packbf(f2, f3);
  ob.z = packbf(f4, f5);
  ob.w = packbf(f6, f7);
  *(uint4*)ap = ob;
}

// ---------------- phase 1: LDS-binned bucket scatter of edges ----------------
// Packed entry: src (17 bits) | local_dst (7 bits) << 17. Bucket = dst>>7.
__global__ __launch_bounds__(512) void k_bucket(const int* __restrict__ ei,
                                                int* __restrict__ bcur,
                                                unsigned int* __restrict__ bbuf) {
  __shared__ int cnt[1024];
  __shared__ int sc[2][1024];
  __shared__ int ofs[1024];
  __shared__ int lcur[1024];
  __shared__ int gbase[1024];
  __shared__ unsigned int stag[CHUNK];       // 32 KB
  __shared__ unsigned short sbkt[CHUNK];     // 16 KB
  int tid = threadIdx.x;
  int base = blockIdx.x * CHUNK;
  int lim = min(CHUNK, NE - base);
  cnt[tid] = 0;
  cnt[tid + 512] = 0;
  __syncthreads();
#pragma unroll
  for (int i = 0; i < CHUNK / 512; ++i) {
    int e = i * 512 + tid;
    if (e < lim) {
      int d = ei[NE + base + e];
      d = min(max(d, 0), NN - 1);
      atomicAdd(&cnt[d >> 7], 1);
    }
  }
  __syncthreads();
  sc[0][tid] = cnt[tid];
  sc[0][tid + 512] = cnt[tid + 512];
  __syncthreads();
  int pp = 0;
  for (int d = 1; d < 1024; d <<= 1) {
    int a0 = sc[pp][tid];
    int a1 = sc[pp][tid + 512];
    if (tid >= d) a0 += sc[pp][tid - d];
    a1 += sc[pp][tid + 512 - d];   // tid+512 >= d always (d <= 512)
    sc[pp ^ 1][tid] = a0;
    sc[pp ^ 1][tid + 512] = a1;
    __syncthreads();
    pp ^= 1;
  }
  ofs[tid] = sc[pp][tid] - cnt[tid];
  ofs[tid + 512] = sc[pp][tid + 512] - cnt[tid + 512];
  lcur[tid] = ofs[tid];
  lcur[tid + 512] = ofs[tid + 512];
  if (tid < NBUK) gbase[tid] = atomicAdd(&bcur[tid], cnt[tid]);
  if (tid + 512 < NBUK) gbase[tid + 512] = atomicAdd(&bcur[tid + 512], cnt[tid + 512]);
  __syncthreads();
#pragma unroll
  for (int i = 0; i < CHUNK / 512; ++i) {
    int e = i * 512 + tid;
    if (e < lim) {
      int s = ei[base + e];
      int d = ei[NE + base + e];
      s = min(max(s, 0), NN - 1);
      d = min(max(d, 0), NN - 1);
      int b = d >> 7;
      int pos = atomicAdd(&lcur[b], 1);
      stag[pos] = (unsigned)s | ((unsigned)(d & 127) << 17);
      sbkt[pos] = (unsigned short)b;
    }
  }
  __syncthreads();
  for (int s = tid; s < lim; s += 512) {
    int b = sbkt[s];
    int off = gbase[b] + (s - ofs[b]);
    if (off < BCAP) bbuf[(size_t)b * BCAP + off] = stag[s];
  }
}

// ---------------- phase 2: per-bucket local CSR (LDS) + mean aggregation ----------------
// 16 groups of 32 lanes; within a group: 2 half-groups of 16 lanes, each half
// gathers one edge's 256B feat row via dwordx4 (16B/lane). Halves combined by
// shfl_xor(16) at the end.
__global__ __launch_bounds__(512) void k_bucket_agg(const unsigned int* __restrict__ bbuf,
                                                    const int* __restrict__ bcnt,
                                                    unsigned short* Abuf) {
  __shared__ unsigned int lcsr[BCAP];   // 11.3 KB
  __shared__ int cnt[128], ofs[128], cur[128];
  __shared__ int sc[2][128];
  int tid = threadIdx.x;
  int b = blockIdx.x;
  int m = min(bcnt[b], BCAP);
  int n0 = b << 7;
  int nb = min(128, NN - n0);
  if (tid < 128) cnt[tid] = 0;
  __syncthreads();
  const unsigned int* bp = bbuf + (size_t)b * BCAP;
  for (int s = tid; s < m; s += 512) {
    unsigned p = bp[s];
    atomicAdd(&cnt[(p >> 17) & 127], 1);
  }
  __syncthreads();
  if (tid < 128) sc[0][tid] = cnt[tid];
  __syncthreads();
  int pp = 0;
  for (int d = 1; d < 128; d <<= 1) {
    if (tid < 128) {
      int v = sc[pp][tid];
      if (tid >= d) v += sc[pp][tid - d];
      sc[pp ^ 1][tid] = v;
    }
    __syncthreads();
    pp ^= 1;
  }
  if (tid < 128) {
    int o = sc[pp][tid] - cnt[tid];
    ofs[tid] = o;
    cur[tid] = o;
  }
  __syncthreads();
  for (int s = tid; s < m; s += 512) {
    unsigned p = bp[s];     // L1-hot second read
    int ld = (p >> 17) & 127;
    int pos = atomicAdd(&cur[ld], 1);
    lcsr[pos] = p & 0x1FFFF;
  }
  __syncthreads();
  int lane = tid & 31;
  int g = tid >> 5;        // 16 groups
  int half = lane >> 4;    // which edge of the pair
  int l16 = lane & 15;     // 16B column chunk within the row
  for (int ln = g; ln < nb; ln += 16) {
    int deg = cnt[ln], beg = ofs[ln];
    float aL[4] = {0.f, 0.f, 0.f, 0.f}, aH[4] = {0.f, 0.f, 0.f, 0.f};
    int j = 0;
#pragma unroll 2
    for (; j + 2 <= deg; j += 2) {
      int s = lcsr[beg + j + half];
      uint4 v = *(const uint4*)(Abuf + (size_t)s * K2 + HID + l16 * 8);
      aL[0] += bflo(v.x); aH[0] += bfhi(v.x);
      aL[1] += bflo(v.y); aH[1] += bfhi(v.y);
      aL[2] += bflo(v.z); aH[2] += bfhi(v.z);
      aL[3] += bflo(v.w); aH[3] += bfhi(v.w);
    }
    if (j < deg && half == 0) {   // odd tail: lanes 0..15 only
      int s = lcsr[beg + j];
      uint4 v = *(const uint4*)(Abuf + (size_t)s * K2 + HID + l16 * 8);
      aL[0] += bflo(v.x); aH[0] += bfhi(v.x);
      aL[1] += bflo(v.y); aH[1] += bfhi(v.y);
      aL[2] += bflo(v.z); aH[2] += bfhi(v.z);
      aL[3] += bflo(v.w); aH[3] += bfhi(v.w);
    }
    float inv = 1.f / fmaxf((float)deg, 1.f);
    uint4 o;
    unsigned* op = &o.x;
#pragma unroll
    for (int i = 0; i < 4; ++i) {
      float lo = aL[i] + __shfl_xor(aL[i], 16);
      float hi = aH[i] + __shfl_xor(aH[i], 16);
      op[i] = packbf(lo * inv, hi * inv);
    }
    if (half == 0)
      *(uint4*)(Abuf + (size_t)(n0 + ln) * K2 + l16 * 8) = o;
  }
}

// ---------------- MFMA GEMM: sage = A[N,256] @ Wcat[128,256]^T + bl; BN2 stats fused ----------------
__global__ __launch_bounds__(256) void k_gemm(
    const unsigned short* __restrict__ A, const unsigned short* __restrict__ Wcat,
    const float* __restrict__ bl, float* __restrict__ sage,
    float* __restrict__ colSum, float* __restrict__ colSq) {
  __shared__ __align__(16) unsigned short Bsh[64][264];  // 64 cols x 256 k, +8 pad
  __shared__ float redS[4][64], redQ[4][64];
  int tid = threadIdx.x;
  int ch = blockIdx.y;  // column half: cols ch*64 .. ch*64+63
  for (int i = tid; i < 64 * 32; i += 256) {
    int j = i >> 5;
    int kg = (i & 31) << 3;
    *(s8v*)&Bsh[j][kg] = *(const s8v*)(Wcat + ((size_t)(ch * 64 + j)) * K2 + kg);
  }
  __syncthreads();
  int w = tid >> 6, l = tid & 63;
  int m16 = l & 15, q = l >> 4;
  float ssum[4] = {0.f, 0.f, 0.f, 0.f}, ssq[4] = {0.f, 0.f, 0.f, 0.f};
  f4v zero4 = {0.f, 0.f, 0.f, 0.f};
  s8v zero8 = {0, 0, 0, 0, 0, 0, 0, 0};
  for (int tile = blockIdx.x; tile < MT; tile += gridDim.x) {
    int row = tile * 64 + w * 16 + m16;
    bool rv = row < NN;
    f4v acc[4];
#pragma unroll
    for (int nt = 0; nt < 4; ++nt) acc[nt] = zero4;
#pragma unroll
    for (int kt = 0; kt < 8; ++kt) {
      s8v a = zero8;
      if (rv) a = *(const s8v*)(A + (size_t)row * K2 + kt * 32 + q * 8);
#pragma unroll
      for (int nt = 0; nt < 4; ++nt) {
        s8v bfr = *(const s8v*)(&Bsh[nt * 16 + m16][kt * 32 + q * 8]);
        acc[nt] = __builtin_amdgcn_mfma_f32_16x16x32_bf16(a, bfr, acc[nt], 0, 0, 0);
      }
    }
    int rbase = tile * 64 + w * 16 + q * 4;
#pragma unroll
    for (int nt = 0; nt < 4; ++nt) {
      int col = ch * 64 + nt * 16 + m16;
      float bv = bl[col];
#pragma unroll
      for (int r4 = 0; r4 < 4; ++r4) {
        int rr = rbase + r4;
        if (rr < NN) {
          float v = acc[nt][r4] + bv;
          sage[(size_t)rr * HID + col] = v;
          ssum[nt] += v;
          ssq[nt] = fmaf(v, v, ssq[nt]);
        }
      }
    }
  }
#pragma unroll
  for (int nt = 0; nt < 4; ++nt) {
    float s = ssum[nt], qq = ssq[nt];
    s += __shfl_xor(s, 16);
    s += __shfl_xor(s, 32);
    qq += __shfl_xor(qq, 16);
    qq += __shfl_xor(qq, 32);
    if (q == 0) {
      redS[w][nt * 16 + m16] = s;
      redQ[w][nt * 16 + m16] = qq;
    }
  }
  __syncthreads();
  if (tid < 64) {
    float s = redS[0][tid] + redS[1][tid] + redS[2][tid] + redS[3][tid];
    float qq = redQ[0][tid] + redQ[1][tid] + redQ[2][tid] + redQ[3][tid];
    atomicAdd(&colSum[ch * 64 + tid], s);
    atomicAdd(&colSq[ch * 64 + tid], qq);
  }
}

// ---------------- BN2 apply, in-place on d_out second half ----------------
__global__ __launch_bounds__(256) void k_bn_apply(float* __restrict__ sage,
                                                  const float* __restrict__ av,
                                                  const float* __restrict__ bv) {
  int i = blockIdx.x * 256 + threadIdx.x;  // float4 index
  if (i < NN * HID / 4) {
    float4 s = ((const float4*)sage)[i];
    int c = (i * 4) & (HID - 1);
    float4 a = *(const float4*)(av + c);
    float4 b = *(const float4*)(bv + c);
    float4 o;
    o.x = fmaf(s.x, a.x, b.x);
    o.y = fmaf(s.y, a.y, b.y);
    o.z = fmaf(s.z, a.z, b.z);
    o.w = fmaf(s.w, a.w, b.w);
    ((float4*)sage)[i] = o;
  }
}

extern "C" void kernel_launch(void* const* d_in, const int* in_sizes, int n_in,
                              void* d_out, int out_size, void* d_ws, size_t ws_size,
                              hipStream_t stream) {
  const float* x   = (const float*)d_in[0];
  const int*   ei  = (const int*)d_in[1];
  const float* W1  = (const float*)d_in[2];
  const float* b1  = (const float*)d_in[3];
  const float* g1  = (const float*)d_in[4];
  const float* be1 = (const float*)d_in[5];
  const float* Wl  = (const float*)d_in[6];
  const float* bl  = (const float*)d_in[7];
  const float* Wr  = (const float*)d_in[8];
  const float* g2  = (const float*)d_in[9];
  const float* be2 = (const float*)d_in[10];

  float* feat_out = (float*)d_out;                      // output 0: feat fp32
  float* sage     = (float*)d_out + (size_t)NN * HID;   // output 1 region (sage, BN2'd in place)

  size_t off = 0;
  auto alloc = [&](size_t bytes) -> void* {
    void* p = (char*)d_ws + off;
    off += (bytes + 255) & ~(size_t)255;
    return p;
  };
  unsigned short* Abuf = (unsigned short*)alloc((size_t)NN * K2 * 2);  // [NN][256] bf16: agg|feat
  unsigned int*   bbuf = (unsigned int*)alloc((size_t)NBUK * BCAP * 4);
  int*            bcur = (int*)alloc((size_t)NBUK * 4);
  float*          stats = (float*)alloc(8 * HID * 4);
  float* colSum1 = stats;
  float* colSq1  = stats + HID;
  float* colSum2 = stats + 2 * HID;
  float* colSq2  = stats + 3 * HID;
  float* a1v     = stats + 4 * HID;
  float* b1v     = stats + 5 * HID;
  float* a2v     = stats + 6 * HID;
  float* b2v     = stats + 7 * HID;
  unsigned short* Wcat = (unsigned short*)alloc((size_t)HID * K2 * 2);
  unsigned short* W1b  = (unsigned short*)alloc((size_t)HID * KP * 2);
  unsigned short* xbf  = (unsigned short*)alloc((size_t)NN * KP * 2);

  int prep_n = HID * K2 + HID * KP + NBUK + 4 * HID;
  k_prep<<<(prep_n + 255) / 256, 256, 0, stream>>>(Wl, Wr, W1, Wcat, W1b, bcur, stats);
  k_xcast<<<(NN * 16 + 255) / 256, 256, 0, stream>>>(x, xbf);
  k_bucket<<<(NE + CHUNK - 1) / CHUNK, 512, 0, stream>>>(ei, bcur, bbuf);
  k_proj_gemm<<<512, 256, 0, stream>>>(xbf, W1b, b1, Abuf, colSum1, colSq1);
  k_bn_final<<<1, HID, 0, stream>>>(colSum1, colSq1, g1, be1, a1v, b1v);
  k_apply<<<(NN * 16 + 255) / 256, 256, 0, stream>>>(feat_out, a1v, b1v, Abuf);
  k_bucket_agg<<<NBUK, 512, 0, stream>>>(bbuf, bcur, Abuf);
  k_gemm<<<dim3(512, 2), 256, 0, stream>>>(Abuf, Wcat, bl, sage, colSum2, colSq2);
  k_bn_final<<<1, HID, 0, stream>>>(colSum2, colSq2, g2, be2, a2v, b2v);
  k_bn_apply<<<(NN * HID / 4 + 255) / 256, 256, 0, stream>>>(sage, a2v, b2v);
}

// Round 5
// 307.348 us; speedup vs baseline: 2.1150x; 1.0621x over previous
//
#include <hip/hip_runtime.h>
#include <hip/hip_bf16.h>

#define NN 100000
#define NE 1600000
#define INDIM 48
#define HID 128
#define K2 256
#define KP 64            // padded K for input projection
#define BN_EPS 1e-5f

// bucket sort parameters: buckets of 128 dst nodes
#define NBUK 782          // ceil(100000/128)
#define BCAP 2816         // mean 2046, sigma~45 -> +17 sigma headroom
#define CHUNK 8192        // edges per phase-1 block

#define MT ((NN + 63) / 64)  // 1563 row tiles of 64

typedef short s8v __attribute__((ext_vector_type(8)));
typedef float f4v __attribute__((ext_vector_type(4)));
typedef float f2v __attribute__((ext_vector_type(2)));

__device__ __forceinline__ unsigned short f2bf(float f) {
    __hip_bfloat16 b = __float2bfloat16(f);
    unsigned short u;
    __builtin_memcpy(&u, &b, 2);
    return u;
}
__device__ __forceinline__ float bflo(unsigned u) { return __uint_as_float(u << 16); }
__device__ __forceinline__ float bfhi(unsigned u) { return __uint_as_float(u & 0xffff0000u); }
__device__ __forceinline__ unsigned packbf(float lo, float hi) {
    return (unsigned)f2bf(lo) | ((unsigned)f2bf(hi) << 16);
}

// ---------------- fused prep: weights->bf16, zero bcur & stats ----------------
__global__ __launch_bounds__(256) void k_prep(const float* __restrict__ Wl, const float* __restrict__ Wr,
                                              const float* __restrict__ W1,
                                              unsigned short* __restrict__ Wcat,
                                              unsigned short* __restrict__ W1b,
                                              int* __restrict__ bcur, float* __restrict__ stats) {
  int i = blockIdx.x * 256 + threadIdx.x;
  if (i < HID * K2) {  // Wcat
    int j = i >> 8, k = i & (K2 - 1);
    float v = (k < HID) ? Wl[j * HID + k] : Wr[j * HID + (k - HID)];
    Wcat[i] = f2bf(v);
  }
  int i2 = i - HID * K2;
  if (i2 >= 0 && i2 < HID * KP) {  // W1b (zero-padded K 48->64)
    int j = i2 >> 6, k = i2 & (KP - 1);
    W1b[i2] = (k < INDIM) ? f2bf(W1[j * INDIM + k]) : (unsigned short)0;
  }
  int i3 = i2 - HID * KP;
  if (i3 >= 0 && i3 < NBUK) bcur[i3] = 0;
  int i4 = i3 - NBUK;
  if (i4 >= 0 && i4 < 4 * HID) stats[i4] = 0.f;
}

// ---------------- x cast: fp32 [NN][48] -> bf16 [NN][64] zero-padded ----------------
__global__ __launch_bounds__(256) void k_xcast(const float* __restrict__ x,
                                               unsigned short* __restrict__ xbf) {
  int i = blockIdx.x * 256 + threadIdx.x;  // quad index: NN*16
  if (i >= NN * 16) return;
  int r = i >> 4, c4 = (i & 15) << 2;
  ushort4 o = {0, 0, 0, 0};
  if (c4 < INDIM) {
    float4 v = *(const float4*)(x + (size_t)r * INDIM + c4);
    o.x = f2bf(v.x);
    o.y = f2bf(v.y);
    o.z = f2bf(v.z);
    o.w = f2bf(v.w);
  }
  *(ushort4*)(xbf + (size_t)r * KP + c4) = o;
}

// ---------------- input projection via MFMA: h = xbf @ W1b^T + b1 ----------------
// h written bf16 into Abuf cols 128..255; BN1 column stats (fp32) fused.
__global__ __launch_bounds__(256) void k_proj_gemm(
    const unsigned short* __restrict__ xbf, const unsigned short* __restrict__ W1b,
    const float* __restrict__ b1, unsigned short* __restrict__ Abuf,
    float* __restrict__ colSum, float* __restrict__ colSq) {
  __shared__ __align__(16) unsigned short Bsh[HID][KP + 8];  // 18.4 KB
  __shared__ float redS[4][HID], redQ[4][HID];
  int tid = threadIdx.x;
  for (int i = tid; i < HID * (KP / 8); i += 256) {
    int j = i >> 3, kg = (i & 7) << 3;
    *(s8v*)&Bsh[j][kg] = *(const s8v*)(W1b + (size_t)j * KP + kg);
  }
  __syncthreads();
  int w = tid >> 6, l = tid & 63;
  int m16 = l & 15, q = l >> 4;
  float bcol[8];
#pragma unroll
  for (int nt = 0; nt < 8; ++nt) bcol[nt] = b1[nt * 16 + m16];
  float ssum[8], ssq[8];
#pragma unroll
  for (int nt = 0; nt < 8; ++nt) { ssum[nt] = 0.f; ssq[nt] = 0.f; }
  f4v zero4 = {0.f, 0.f, 0.f, 0.f};
  s8v zero8 = {0, 0, 0, 0, 0, 0, 0, 0};
  for (int tile = blockIdx.x; tile < MT; tile += gridDim.x) {
    int row = tile * 64 + w * 16 + m16;
    bool rv = row < NN;
    f4v acc[8];
#pragma unroll
    for (int nt = 0; nt < 8; ++nt) acc[nt] = zero4;
#pragma unroll
    for (int kt = 0; kt < 2; ++kt) {
      s8v a = zero8;
      if (rv) a = *(const s8v*)(xbf + (size_t)row * KP + kt * 32 + q * 8);
#pragma unroll
      for (int nt = 0; nt < 8; ++nt) {
        s8v b = *(const s8v*)(&Bsh[nt * 16 + m16][kt * 32 + q * 8]);
        acc[nt] = __builtin_amdgcn_mfma_f32_16x16x32_bf16(a, b, acc[nt], 0, 0, 0);
      }
    }
    int rbase = tile * 64 + w * 16 + q * 4;
#pragma unroll
    for (int nt = 0; nt < 8; ++nt) {
      int col = nt * 16 + m16;
#pragma unroll
      for (int r4 = 0; r4 < 4; ++r4) {
        int rr = rbase + r4;
        if (rr < NN) {
          float v = acc[nt][r4] + bcol[nt];
          Abuf[(size_t)rr * K2 + HID + col] = f2bf(v);
          ssum[nt] += v;
          ssq[nt] = fmaf(v, v, ssq[nt]);
        }
      }
    }
  }
#pragma unroll
  for (int nt = 0; nt < 8; ++nt) {
    float s = ssum[nt], qq = ssq[nt];
    s += __shfl_xor(s, 16);
    s += __shfl_xor(s, 32);
    qq += __shfl_xor(qq, 16);
    qq += __shfl_xor(qq, 32);
    if (q == 0) {
      redS[w][nt * 16 + m16] = s;
      redQ[w][nt * 16 + m16] = qq;
    }
  }
  __syncthreads();
  if (tid < HID) {
    float s = redS[0][tid] + redS[1][tid] + redS[2][tid] + redS[3][tid];
    float qq = redQ[0][tid] + redQ[1][tid] + redQ[2][tid] + redQ[3][tid];
    atomicAdd(&colSum[tid], s);
    atomicAdd(&colSq[tid], qq);
  }
}

// ---------------- BN finalize: a = g*rsqrt(var+eps), b = be - mu*a ----------------
__global__ void k_bn_final(const float* __restrict__ sum, const float* __restrict__ sq,
                           const float* __restrict__ gamma, const float* __restrict__ beta,
                           float* __restrict__ av, float* __restrict__ bv) {
  int c = threadIdx.x;
  float mu = sum[c] * (1.0f / NN);
  float var = fmaxf(sq[c] * (1.0f / NN) - mu * mu, 0.f);
  float a = gamma[c] * rsqrtf(var + BN_EPS);
  av[c] = a;
  bv[c] = beta[c] - mu * a;
}

// ---------------- BN1+ReLU apply: h(bf16)->feat fp32 + bf16 (Abuf) + fp8 (gather table) ----------------
__global__ __launch_bounds__(256) void k_apply(float* __restrict__ feat,
                                               const float* __restrict__ av,
                                               const float* __restrict__ bv,
                                               unsigned short* __restrict__ A,
                                               unsigned char* __restrict__ feat8) {
  int i = blockIdx.x * 256 + threadIdx.x;  // oct index: NN*16
  if (i >= NN * 16) return;
  int r = i >> 4, c8 = (i & 15) << 3;
  unsigned short* ap = A + (size_t)r * K2 + HID + c8;
  uint4 hv = *(const uint4*)ap;
  float4 a0 = *(const float4*)(av + c8);
  float4 a1 = *(const float4*)(av + c8 + 4);
  float4 b0 = *(const float4*)(bv + c8);
  float4 b1 = *(const float4*)(bv + c8 + 4);
  float f0 = fmaxf(fmaf(bflo(hv.x), a0.x, b0.x), 0.f);
  float f1 = fmaxf(fmaf(bfhi(hv.x), a0.y, b0.y), 0.f);
  float f2 = fmaxf(fmaf(bflo(hv.y), a0.z, b0.z), 0.f);
  float f3 = fmaxf(fmaf(bfhi(hv.y), a0.w, b0.w), 0.f);
  float f4 = fmaxf(fmaf(bflo(hv.z), a1.x, b1.x), 0.f);
  float f5 = fmaxf(fmaf(bfhi(hv.z), a1.y, b1.y), 0.f);
  float f6 = fmaxf(fmaf(bflo(hv.w), a1.z, b1.z), 0.f);
  float f7 = fmaxf(fmaf(bfhi(hv.w), a1.w, b1.w), 0.f);
  float4 o0 = {f0, f1, f2, f3}, o1 = {f4, f5, f6, f7};
  *(float4*)(feat + (size_t)r * HID + c8) = o0;
  *(float4*)(feat + (size_t)r * HID + c8 + 4) = o1;
  uint4 ob;
  ob.x = packbf(f0, f1);
  ob.y = packbf(f2, f3);
  ob.z = packbf(f4, f5);
  ob.w = packbf(f6, f7);
  *(uint4*)ap = ob;
  // fp8 e4m3 gather copy (HW round): 8 vals -> 2 dwords
  unsigned p0 = __builtin_amdgcn_cvt_pk_fp8_f32(f0, f1, 0u, false);
  p0 = __builtin_amdgcn_cvt_pk_fp8_f32(f2, f3, p0, true);
  unsigned p1 = __builtin_amdgcn_cvt_pk_fp8_f32(f4, f5, 0u, false);
  p1 = __builtin_amdgcn_cvt_pk_fp8_f32(f6, f7, p1, true);
  uint2 o8 = {p0, p1};
  *(uint2*)(feat8 + (size_t)r * HID + c8) = o8;
}

// ---------------- phase 1: LDS-binned bucket scatter of edges ----------------
// Packed entry: src (17 bits) | local_dst (7 bits) << 17. Bucket = dst>>7.
__global__ __launch_bounds__(512) void k_bucket(const int* __restrict__ ei,
                                                int* __restrict__ bcur,
                                                unsigned int* __restrict__ bbuf) {
  __shared__ int cnt[1024];
  __shared__ int sc[2][1024];
  __shared__ int ofs[1024];
  __shared__ int lcur[1024];
  __shared__ int gbase[1024];
  __shared__ unsigned int stag[CHUNK];       // 32 KB
  __shared__ unsigned short sbkt[CHUNK];     // 16 KB
  int tid = threadIdx.x;
  int base = blockIdx.x * CHUNK;
  int lim = min(CHUNK, NE - base);
  cnt[tid] = 0;
  cnt[tid + 512] = 0;
  __syncthreads();
#pragma unroll
  for (int i = 0; i < CHUNK / 512; ++i) {
    int e = i * 512 + tid;
    if (e < lim) {
      int d = ei[NE + base + e];
      d = min(max(d, 0), NN - 1);
      atomicAdd(&cnt[d >> 7], 1);
    }
  }
  __syncthreads();
  sc[0][tid] = cnt[tid];
  sc[0][tid + 512] = cnt[tid + 512];
  __syncthreads();
  int pp = 0;
  for (int d = 1; d < 1024; d <<= 1) {
    int a0 = sc[pp][tid];
    int a1 = sc[pp][tid + 512];
    if (tid >= d) a0 += sc[pp][tid - d];
    a1 += sc[pp][tid + 512 - d];   // tid+512 >= d always (d <= 512)
    sc[pp ^ 1][tid] = a0;
    sc[pp ^ 1][tid + 512] = a1;
    __syncthreads();
    pp ^= 1;
  }
  ofs[tid] = sc[pp][tid] - cnt[tid];
  ofs[tid + 512] = sc[pp][tid + 512] - cnt[tid + 512];
  lcur[tid] = ofs[tid];
  lcur[tid + 512] = ofs[tid + 512];
  if (tid < NBUK) gbase[tid] = atomicAdd(&bcur[tid], cnt[tid]);
  if (tid + 512 < NBUK) gbase[tid + 512] = atomicAdd(&bcur[tid + 512], cnt[tid + 512]);
  __syncthreads();
#pragma unroll
  for (int i = 0; i < CHUNK / 512; ++i) {
    int e = i * 512 + tid;
    if (e < lim) {
      int s = ei[base + e];
      int d = ei[NE + base + e];
      s = min(max(s, 0), NN - 1);
      d = min(max(d, 0), NN - 1);
      int b = d >> 7;
      int pos = atomicAdd(&lcur[b], 1);
      stag[pos] = (unsigned)s | ((unsigned)(d & 127) << 17);
      sbkt[pos] = (unsigned short)b;
    }
  }
  __syncthreads();
  for (int s = tid; s < lim; s += 512) {
    int b = sbkt[s];
    int off = gbase[b] + (s - ofs[b]);
    if (off < BCAP) bbuf[(size_t)b * BCAP + off] = stag[s];
  }
}

// ---------------- phase 2: per-bucket local CSR (LDS) + fp8 mean aggregation ----------------
// 16 groups of 32 lanes; each group processes 4 edges/iter (8 lanes x 16B = one
// 128B fp8 row per edge). HW fp8->f32 decode; fp32 accumulate; bf16 agg out.
__global__ __launch_bounds__(512) void k_bucket_agg(const unsigned int* __restrict__ bbuf,
                                                    const int* __restrict__ bcnt,
                                                    const unsigned char* __restrict__ feat8,
                                                    unsigned short* __restrict__ Abuf) {
  __shared__ unsigned int lcsr[BCAP];   // 11.3 KB
  __shared__ int cnt[128], ofs[128], cur[128];
  __shared__ int sc[2][128];
  int tid = threadIdx.x;
  int b = blockIdx.x;
  int m = min(bcnt[b], BCAP);
  int n0 = b << 7;
  int nb = min(128, NN - n0);
  if (tid < 128) cnt[tid] = 0;
  __syncthreads();
  const unsigned int* bp = bbuf + (size_t)b * BCAP;
  for (int s = tid; s < m; s += 512) {
    unsigned p = bp[s];
    atomicAdd(&cnt[(p >> 17) & 127], 1);
  }
  __syncthreads();
  if (tid < 128) sc[0][tid] = cnt[tid];
  __syncthreads();
  int pp = 0;
  for (int d = 1; d < 128; d <<= 1) {
    if (tid < 128) {
      int v = sc[pp][tid];
      if (tid >= d) v += sc[pp][tid - d];
      sc[pp ^ 1][tid] = v;
    }
    __syncthreads();
    pp ^= 1;
  }
  if (tid < 128) {
    int o = sc[pp][tid] - cnt[tid];
    ofs[tid] = o;
    cur[tid] = o;
  }
  __syncthreads();
  for (int s = tid; s < m; s += 512) {
    unsigned p = bp[s];     // L1-hot second read
    int ld = (p >> 17) & 127;
    int pos = atomicAdd(&cur[ld], 1);
    lcsr[pos] = p & 0x1FFFF;
  }
  __syncthreads();
  int lane = tid & 31;
  int g = tid >> 5;             // 16 groups
  int half = (lane >> 3) & 3;   // which of 4 edges in the iter
  int l8 = lane & 7;            // 16-col chunk within the row
  for (int ln = g; ln < nb; ln += 16) {
    int deg = cnt[ln], beg = ofs[ln];
    float ac[16];
#pragma unroll
    for (int i = 0; i < 16; ++i) ac[i] = 0.f;
#pragma unroll 2
    for (int j = 0; j < deg; j += 4) {
      int idx = j + half;
      uint4 v = {0u, 0u, 0u, 0u};
      if (idx < deg) {
        int s = lcsr[beg + idx];
        v = *(const uint4*)(feat8 + (size_t)s * HID + l8 * 16);
      }
      f2v d;
      d = __builtin_amdgcn_cvt_pk_f32_fp8(v.x, false); ac[0] += d.x;  ac[1] += d.y;
      d = __builtin_amdgcn_cvt_pk_f32_fp8(v.x, true);  ac[2] += d.x;  ac[3] += d.y;
      d = __builtin_amdgcn_cvt_pk_f32_fp8(v.y, false); ac[4] += d.x;  ac[5] += d.y;
      d = __builtin_amdgcn_cvt_pk_f32_fp8(v.y, true);  ac[6] += d.x;  ac[7] += d.y;
      d = __builtin_amdgcn_cvt_pk_f32_fp8(v.z, false); ac[8] += d.x;  ac[9] += d.y;
      d = __builtin_amdgcn_cvt_pk_f32_fp8(v.z, true);  ac[10] += d.x; ac[11] += d.y;
      d = __builtin_amdgcn_cvt_pk_f32_fp8(v.w, false); ac[12] += d.x; ac[13] += d.y;
      d = __builtin_amdgcn_cvt_pk_f32_fp8(v.w, true);  ac[14] += d.x; ac[15] += d.y;
    }
#pragma unroll
    for (int i = 0; i < 16; ++i) {
      ac[i] += __shfl_xor(ac[i], 8);
      ac[i] += __shfl_xor(ac[i], 16);
    }
    if (half == 0) {
      float inv = 1.f / fmaxf((float)deg, 1.f);
      uint4 o0, o1;
      o0.x = packbf(ac[0] * inv, ac[1] * inv);
      o0.y = packbf(ac[2] * inv, ac[3] * inv);
      o0.z = packbf(ac[4] * inv, ac[5] * inv);
      o0.w = packbf(ac[6] * inv, ac[7] * inv);
      o1.x = packbf(ac[8] * inv, ac[9] * inv);
      o1.y = packbf(ac[10] * inv, ac[11] * inv);
      o1.z = packbf(ac[12] * inv, ac[13] * inv);
      o1.w = packbf(ac[14] * inv, ac[15] * inv);
      unsigned short* op = Abuf + (size_t)(n0 + ln) * K2 + l8 * 16;
      *(uint4*)op = o0;
      *(uint4*)(op + 8) = o1;
    }
  }
}

// ---------------- MFMA GEMM: sage = A[N,256] @ Wcat[128,256]^T + bl; BN2 stats fused ----------------
__global__ __launch_bounds__(256) void k_gemm(
    const unsigned short* __restrict__ A, const unsigned short* __restrict__ Wcat,
    const float* __restrict__ bl, float* __restrict__ sage,
    float* __restrict__ colSum, float* __restrict__ colSq) {
  __shared__ __align__(16) unsigned short Bsh[64][264];  // 64 cols x 256 k, +8 pad
  __shared__ float redS[4][64], redQ[4][64];
  int tid = threadIdx.x;
  int ch = blockIdx.y;  // column half: cols ch*64 .. ch*64+63
  for (int i = tid; i < 64 * 32; i += 256) {
    int j = i >> 5;
    int kg = (i & 31) << 3;
    *(s8v*)&Bsh[j][kg] = *(const s8v*)(Wcat + ((size_t)(ch * 64 + j)) * K2 + kg);
  }
  __syncthreads();
  int w = tid >> 6, l = tid & 63;
  int m16 = l & 15, q = l >> 4;
  float ssum[4] = {0.f, 0.f, 0.f, 0.f}, ssq[4] = {0.f, 0.f, 0.f, 0.f};
  f4v zero4 = {0.f, 0.f, 0.f, 0.f};
  s8v zero8 = {0, 0, 0, 0, 0, 0, 0, 0};
  for (int tile = blockIdx.x; tile < MT; tile += gridDim.x) {
    int row = tile * 64 + w * 16 + m16;
    bool rv = row < NN;
    f4v acc[4];
#pragma unroll
    for (int nt = 0; nt < 4; ++nt) acc[nt] = zero4;
#pragma unroll
    for (int kt = 0; kt < 8; ++kt) {
      s8v a = zero8;
      if (rv) a = *(const s8v*)(A + (size_t)row * K2 + kt * 32 + q * 8);
#pragma unroll
      for (int nt = 0; nt < 4; ++nt) {
        s8v bfr = *(const s8v*)(&Bsh[nt * 16 + m16][kt * 32 + q * 8]);
        acc[nt] = __builtin_amdgcn_mfma_f32_16x16x32_bf16(a, bfr, acc[nt], 0, 0, 0);
      }
    }
    int rbase = tile * 64 + w * 16 + q * 4;
#pragma unroll
    for (int nt = 0; nt < 4; ++nt) {
      int col = ch * 64 + nt * 16 + m16;
      float bv = bl[col];
#pragma unroll
      for (int r4 = 0; r4 < 4; ++r4) {
        int rr = rbase + r4;
        if (rr < NN) {
          float v = acc[nt][r4] + bv;
          sage[(size_t)rr * HID + col] = v;
          ssum[nt] += v;
          ssq[nt] = fmaf(v, v, ssq[nt]);
        }
      }
    }
  }
#pragma unroll
  for (int nt = 0; nt < 4; ++nt) {
    float s = ssum[nt], qq = ssq[nt];
    s += __shfl_xor(s, 16);
    s += __shfl_xor(s, 32);
    qq += __shfl_xor(qq, 16);
    qq += __shfl_xor(qq, 32);
    if (q == 0) {
      redS[w][nt * 16 + m16] = s;
      redQ[w][nt * 16 + m16] = qq;
    }
  }
  __syncthreads();
  if (tid < 64) {
    float s = redS[0][tid] + redS[1][tid] + redS[2][tid] + redS[3][tid];
    float qq = redQ[0][tid] + redQ[1][tid] + redQ[2][tid] + redQ[3][tid];
    atomicAdd(&colSum[ch * 64 + tid], s);
    atomicAdd(&colSq[ch * 64 + tid], qq);
  }
}

// ---------------- BN2 apply, in-place on d_out second half ----------------
__global__ __launch_bounds__(256) void k_bn_apply(float* __restrict__ sage,
                                                  const float* __restrict__ av,
                                                  const float* __restrict__ bv) {
  int i = blockIdx.x * 256 + threadIdx.x;  // float4 index
  if (i < NN * HID / 4) {
    float4 s = ((const float4*)sage)[i];
    int c = (i * 4) & (HID - 1);
    float4 a = *(const float4*)(av + c);
    float4 b = *(const float4*)(bv + c);
    float4 o;
    o.x = fmaf(s.x, a.x, b.x);
    o.y = fmaf(s.y, a.y, b.y);
    o.z = fmaf(s.z, a.z, b.z);
    o.w = fmaf(s.w, a.w, b.w);
    ((float4*)sage)[i] = o;
  }
}

extern "C" void kernel_launch(void* const* d_in, const int* in_sizes, int n_in,
                              void* d_out, int out_size, void* d_ws, size_t ws_size,
                              hipStream_t stream) {
  const float* x   = (const float*)d_in[0];
  const int*   ei  = (const int*)d_in[1];
  const float* W1  = (const float*)d_in[2];
  const float* b1  = (const float*)d_in[3];
  const float* g1  = (const float*)d_in[4];
  const float* be1 = (const float*)d_in[5];
  const float* Wl  = (const float*)d_in[6];
  const float* bl  = (const float*)d_in[7];
  const float* Wr  = (const float*)d_in[8];
  const float* g2  = (const float*)d_in[9];
  const float* be2 = (const float*)d_in[10];

  float* feat_out = (float*)d_out;                      // output 0: feat fp32
  float* sage     = (float*)d_out + (size_t)NN * HID;   // output 1 region (sage, BN2'd in place)

  size_t off = 0;
  auto alloc = [&](size_t bytes) -> void* {
    void* p = (char*)d_ws + off;
    off += (bytes + 255) & ~(size_t)255;
    return p;
  };
  unsigned short* Abuf = (unsigned short*)alloc((size_t)NN * K2 * 2);  // [NN][256] bf16: agg|feat
  unsigned char*  feat8 = (unsigned char*)alloc((size_t)NN * HID);     // fp8 e4m3 gather table
  unsigned int*   bbuf = (unsigned int*)alloc((size_t)NBUK * BCAP * 4);
  int*            bcur = (int*)alloc((size_t)NBUK * 4);
  float*          stats = (float*)alloc(8 * HID * 4);
  float* colSum1 = stats;
  float* colSq1  = stats + HID;
  float* colSum2 = stats + 2 * HID;
  float* colSq2  = stats + 3 * HID;
  float* a1v     = stats + 4 * HID;
  float* b1v     = stats + 5 * HID;
  float* a2v     = stats + 6 * HID;
  float* b2v     = stats + 7 * HID;
  unsigned short* Wcat = (unsigned short*)alloc((size_t)HID * K2 * 2);
  unsigned short* W1b  = (unsigned short*)alloc((size_t)HID * KP * 2);
  unsigned short* xbf  = (unsigned short*)alloc((size_t)NN * KP * 2);

  int prep_n = HID * K2 + HID * KP + NBUK + 4 * HID;
  k_prep<<<(prep_n + 255) / 256, 256, 0, stream>>>(Wl, Wr, W1, Wcat, W1b, bcur, stats);
  k_xcast<<<(NN * 16 + 255) / 256, 256, 0, stream>>>(x, xbf);
  k_bucket<<<(NE + CHUNK - 1) / CHUNK, 512, 0, stream>>>(ei, bcur, bbuf);
  k_proj_gemm<<<512, 256, 0, stream>>>(xbf, W1b, b1, Abuf, colSum1, colSq1);
  k_bn_final<<<1, HID, 0, stream>>>(colSum1, colSq1, g1, be1, a1v, b1v);
  k_apply<<<(NN * 16 + 255) / 256, 256, 0, stream>>>(feat_out, a1v, b1v, Abuf, feat8);
  k_bucket_agg<<<NBUK, 512, 0, stream>>>(bbuf, bcur, feat8, Abuf);
  k_gemm<<<dim3(512, 2), 256, 0, stream>>>(Abuf, Wcat, bl, sage, colSum2, colSq2);
  k_bn_final<<<1, HID, 0, stream>>>(colSum2, colSq2, g2, be2, a2v, b2v);
  k_bn_apply<<<(NN * HID / 4 + 255) / 256, 256, 0, stream>>>(sage, a2v, b2v);
}

// Round 6
// 294.299 us; speedup vs baseline: 2.2087x; 1.0443x over previous
//
#include <hip/hip_runtime.h>
#include <hip/hip_bf16.h>

#define NN 100000
#define NE 1600000
#define INDIM 48
#define HID 128
#define K2 256
#define KP 64            // padded K for input projection
#define BN_EPS 1e-5f

// bucket sort parameters: buckets of 128 dst nodes
#define NBUK 782          // ceil(100000/128)
#define BCAP 2816         // mean 2046, sigma~45 -> +17 sigma headroom
#define CHUNK 8192        // edges per phase-1 block

#define MT ((NN + 63) / 64)    // 1563 row tiles of 64 (proj gemm)
#define MT2 ((NN + 127) / 128) // 782 row tiles of 128 (sage gemm)

typedef short s8v __attribute__((ext_vector_type(8)));
typedef float f4v __attribute__((ext_vector_type(4)));
typedef float f2v __attribute__((ext_vector_type(2)));

__device__ __forceinline__ unsigned short f2bf(float f) {
    __hip_bfloat16 b = __float2bfloat16(f);
    unsigned short u;
    __builtin_memcpy(&u, &b, 2);
    return u;
}
__device__ __forceinline__ float bflo(unsigned u) { return __uint_as_float(u << 16); }
__device__ __forceinline__ float bfhi(unsigned u) { return __uint_as_float(u & 0xffff0000u); }
__device__ __forceinline__ unsigned packbf(float lo, float hi) {
    return (unsigned)f2bf(lo) | ((unsigned)f2bf(hi) << 16);
}

// ---------------- x cast (fp32 [NN][48] -> bf16 [NN][64]) + fused prep ----------------
// Prep work (weights->bf16, zero bcur/stats) rides on the same grid: its index
// range (~42k) is far below the xcast range (1.6M), no ordering hazards.
__global__ __launch_bounds__(256) void k_xcast(const float* __restrict__ x,
                                               unsigned short* __restrict__ xbf,
                                               const float* __restrict__ Wl, const float* __restrict__ Wr,
                                               const float* __restrict__ W1,
                                               unsigned short* __restrict__ Wcat,
                                               unsigned short* __restrict__ W1b,
                                               int* __restrict__ bcur, float* __restrict__ stats) {
  int i = blockIdx.x * 256 + threadIdx.x;  // quad index: NN*16
  if (i < NN * 16) {
    int r = i >> 4, c4 = (i & 15) << 2;
    ushort4 o = {0, 0, 0, 0};
    if (c4 < INDIM) {
      float4 v = *(const float4*)(x + (size_t)r * INDIM + c4);
      o.x = f2bf(v.x);
      o.y = f2bf(v.y);
      o.z = f2bf(v.z);
      o.w = f2bf(v.w);
    }
    *(ushort4*)(xbf + (size_t)r * KP + c4) = o;
  }
  if (i < HID * K2) {  // Wcat
    int j = i >> 8, k = i & (K2 - 1);
    float v = (k < HID) ? Wl[j * HID + k] : Wr[j * HID + (k - HID)];
    Wcat[i] = f2bf(v);
  }
  int i2 = i - HID * K2;
  if (i2 >= 0 && i2 < HID * KP) {  // W1b (zero-padded K 48->64)
    int j = i2 >> 6, k = i2 & (KP - 1);
    W1b[i2] = (k < INDIM) ? f2bf(W1[j * INDIM + k]) : (unsigned short)0;
  }
  int i3 = i2 - HID * KP;
  if (i3 >= 0 && i3 < NBUK) bcur[i3] = 0;
  int i4 = i3 - NBUK;
  if (i4 >= 0 && i4 < 4 * HID) stats[i4] = 0.f;
}

// ---------------- input projection via MFMA: h = xbf @ W1b^T + b1 ----------------
// h written bf16 into Abuf cols 128..255; BN1 column stats (fp32) fused.
__global__ __launch_bounds__(256) void k_proj_gemm(
    const unsigned short* __restrict__ xbf, const unsigned short* __restrict__ W1b,
    const float* __restrict__ b1, unsigned short* __restrict__ Abuf,
    float* __restrict__ colSum, float* __restrict__ colSq) {
  __shared__ __align__(16) unsigned short Bsh[HID][KP + 8];  // 18.4 KB
  __shared__ float redS[4][HID], redQ[4][HID];
  int tid = threadIdx.x;
  for (int i = tid; i < HID * (KP / 8); i += 256) {
    int j = i >> 3, kg = (i & 7) << 3;
    *(s8v*)&Bsh[j][kg] = *(const s8v*)(W1b + (size_t)j * KP + kg);
  }
  __syncthreads();
  int w = tid >> 6, l = tid & 63;
  int m16 = l & 15, q = l >> 4;
  float bcol[8];
#pragma unroll
  for (int nt = 0; nt < 8; ++nt) bcol[nt] = b1[nt * 16 + m16];
  float ssum[8], ssq[8];
#pragma unroll
  for (int nt = 0; nt < 8; ++nt) { ssum[nt] = 0.f; ssq[nt] = 0.f; }
  f4v zero4 = {0.f, 0.f, 0.f, 0.f};
  s8v zero8 = {0, 0, 0, 0, 0, 0, 0, 0};
  for (int tile = blockIdx.x; tile < MT; tile += gridDim.x) {
    int row = tile * 64 + w * 16 + m16;
    bool rv = row < NN;
    f4v acc[8];
#pragma unroll
    for (int nt = 0; nt < 8; ++nt) acc[nt] = zero4;
#pragma unroll
    for (int kt = 0; kt < 2; ++kt) {
      s8v a = zero8;
      if (rv) a = *(const s8v*)(xbf + (size_t)row * KP + kt * 32 + q * 8);
#pragma unroll
      for (int nt = 0; nt < 8; ++nt) {
        s8v b = *(const s8v*)(&Bsh[nt * 16 + m16][kt * 32 + q * 8]);
        acc[nt] = __builtin_amdgcn_mfma_f32_16x16x32_bf16(a, b, acc[nt], 0, 0, 0);
      }
    }
    int rbase = tile * 64 + w * 16 + q * 4;
#pragma unroll
    for (int nt = 0; nt < 8; ++nt) {
      int col = nt * 16 + m16;
#pragma unroll
      for (int r4 = 0; r4 < 4; ++r4) {
        int rr = rbase + r4;
        if (rr < NN) {
          float v = acc[nt][r4] + bcol[nt];
          Abuf[(size_t)rr * K2 + HID + col] = f2bf(v);
          ssum[nt] += v;
          ssq[nt] = fmaf(v, v, ssq[nt]);
        }
      }
    }
  }
#pragma unroll
  for (int nt = 0; nt < 8; ++nt) {
    float s = ssum[nt], qq = ssq[nt];
    s += __shfl_xor(s, 16);
    s += __shfl_xor(s, 32);
    qq += __shfl_xor(qq, 16);
    qq += __shfl_xor(qq, 32);
    if (q == 0) {
      redS[w][nt * 16 + m16] = s;
      redQ[w][nt * 16 + m16] = qq;
    }
  }
  __syncthreads();
  if (tid < HID) {
    float s = redS[0][tid] + redS[1][tid] + redS[2][tid] + redS[3][tid];
    float qq = redQ[0][tid] + redQ[1][tid] + redQ[2][tid] + redQ[3][tid];
    atomicAdd(&colSum[tid], s);
    atomicAdd(&colSq[tid], qq);
  }
}

// ---------------- BN finalize: a = g*rsqrt(var+eps), b = be - mu*a ----------------
__global__ void k_bn_final(const float* __restrict__ sum, const float* __restrict__ sq,
                           const float* __restrict__ gamma, const float* __restrict__ beta,
                           float* __restrict__ av, float* __restrict__ bv) {
  int c = threadIdx.x;
  float mu = sum[c] * (1.0f / NN);
  float var = fmaxf(sq[c] * (1.0f / NN) - mu * mu, 0.f);
  float a = gamma[c] * rsqrtf(var + BN_EPS);
  av[c] = a;
  bv[c] = beta[c] - mu * a;
}

// ---------------- BN1+ReLU apply: h(bf16)->feat fp32 + bf16 (Abuf) + fp8 (gather table) ----------------
__global__ __launch_bounds__(256) void k_apply(float* __restrict__ feat,
                                               const float* __restrict__ av,
                                               const float* __restrict__ bv,
                                               unsigned short* __restrict__ A,
                                               unsigned char* __restrict__ feat8) {
  int i = blockIdx.x * 256 + threadIdx.x;  // oct index: NN*16
  if (i >= NN * 16) return;
  int r = i >> 4, c8 = (i & 15) << 3;
  unsigned short* ap = A + (size_t)r * K2 + HID + c8;
  uint4 hv = *(const uint4*)ap;
  float4 a0 = *(const float4*)(av + c8);
  float4 a1 = *(const float4*)(av + c8 + 4);
  float4 b0 = *(const float4*)(bv + c8);
  float4 b1 = *(const float4*)(bv + c8 + 4);
  float f0 = fmaxf(fmaf(bflo(hv.x), a0.x, b0.x), 0.f);
  float f1 = fmaxf(fmaf(bfhi(hv.x), a0.y, b0.y), 0.f);
  float f2 = fmaxf(fmaf(bflo(hv.y), a0.z, b0.z), 0.f);
  float f3 = fmaxf(fmaf(bfhi(hv.y), a0.w, b0.w), 0.f);
  float f4 = fmaxf(fmaf(bflo(hv.z), a1.x, b1.x), 0.f);
  float f5 = fmaxf(fmaf(bfhi(hv.z), a1.y, b1.y), 0.f);
  float f6 = fmaxf(fmaf(bflo(hv.w), a1.z, b1.z), 0.f);
  float f7 = fmaxf(fmaf(bfhi(hv.w), a1.w, b1.w), 0.f);
  float4 o0 = {f0, f1, f2, f3}, o1 = {f4, f5, f6, f7};
  *(float4*)(feat + (size_t)r * HID + c8) = o0;
  *(float4*)(feat + (size_t)r * HID + c8 + 4) = o1;
  uint4 ob;
  ob.x = packbf(f0, f1);
  ob.y = packbf(f2, f3);
  ob.z = packbf(f4, f5);
  ob.w = packbf(f6, f7);
  *(uint4*)ap = ob;
  // fp8 e4m3 gather copy (HW round): 8 vals -> 2 dwords
  unsigned p0 = __builtin_amdgcn_cvt_pk_fp8_f32(f0, f1, 0u, false);
  p0 = __builtin_amdgcn_cvt_pk_fp8_f32(f2, f3, p0, true);
  unsigned p1 = __builtin_amdgcn_cvt_pk_fp8_f32(f4, f5, 0u, false);
  p1 = __builtin_amdgcn_cvt_pk_fp8_f32(f6, f7, p1, true);
  uint2 o8 = {p0, p1};
  *(uint2*)(feat8 + (size_t)r * HID + c8) = o8;
}

// ---------------- phase 1: LDS-binned bucket scatter of edges ----------------
// Packed entry: src (17 bits) | local_dst (7 bits) << 17. Bucket = dst>>7.
__global__ __launch_bounds__(512) void k_bucket(const int* __restrict__ ei,
                                                int* __restrict__ bcur,
                                                unsigned int* __restrict__ bbuf) {
  __shared__ int cnt[1024];
  __shared__ int sc[2][1024];
  __shared__ int ofs[1024];
  __shared__ int lcur[1024];
  __shared__ int gbase[1024];
  __shared__ unsigned int stag[CHUNK];       // 32 KB
  __shared__ unsigned short sbkt[CHUNK];     // 16 KB
  int tid = threadIdx.x;
  int base = blockIdx.x * CHUNK;
  int lim = min(CHUNK, NE - base);
  cnt[tid] = 0;
  cnt[tid + 512] = 0;
  __syncthreads();
#pragma unroll
  for (int i = 0; i < CHUNK / 512; ++i) {
    int e = i * 512 + tid;
    if (e < lim) {
      int d = ei[NE + base + e];
      d = min(max(d, 0), NN - 1);
      atomicAdd(&cnt[d >> 7], 1);
    }
  }
  __syncthreads();
  sc[0][tid] = cnt[tid];
  sc[0][tid + 512] = cnt[tid + 512];
  __syncthreads();
  int pp = 0;
  for (int d = 1; d < 1024; d <<= 1) {
    int a0 = sc[pp][tid];
    int a1 = sc[pp][tid + 512];
    if (tid >= d) a0 += sc[pp][tid - d];
    a1 += sc[pp][tid + 512 - d];   // tid+512 >= d always (d <= 512)
    sc[pp ^ 1][tid] = a0;
    sc[pp ^ 1][tid + 512] = a1;
    __syncthreads();
    pp ^= 1;
  }
  ofs[tid] = sc[pp][tid] - cnt[tid];
  ofs[tid + 512] = sc[pp][tid + 512] - cnt[tid + 512];
  lcur[tid] = ofs[tid];
  lcur[tid + 512] = ofs[tid + 512];
  if (tid < NBUK) gbase[tid] = atomicAdd(&bcur[tid], cnt[tid]);
  if (tid + 512 < NBUK) gbase[tid + 512] = atomicAdd(&bcur[tid + 512], cnt[tid + 512]);
  __syncthreads();
#pragma unroll
  for (int i = 0; i < CHUNK / 512; ++i) {
    int e = i * 512 + tid;
    if (e < lim) {
      int s = ei[base + e];
      int d = ei[NE + base + e];
      s = min(max(s, 0), NN - 1);
      d = min(max(d, 0), NN - 1);
      int b = d >> 7;
      int pos = atomicAdd(&lcur[b], 1);
      stag[pos] = (unsigned)s | ((unsigned)(d & 127) << 17);
      sbkt[pos] = (unsigned short)b;
    }
  }
  __syncthreads();
  for (int s = tid; s < lim; s += 512) {
    int b = sbkt[s];
    int off = gbase[b] + (s - ofs[b]);
    if (off < BCAP) bbuf[(size_t)b * BCAP + off] = stag[s];
  }
}

// ---------------- phase 2: per-bucket local CSR (LDS) + fp8 mean aggregation ----------------
__global__ __launch_bounds__(512) void k_bucket_agg(const unsigned int* __restrict__ bbuf,
                                                    const int* __restrict__ bcnt,
                                                    const unsigned char* __restrict__ feat8,
                                                    unsigned short* __restrict__ Abuf) {
  __shared__ unsigned int lcsr[BCAP];   // 11.3 KB
  __shared__ int cnt[128], ofs[128], cur[128];
  __shared__ int sc[2][128];
  int tid = threadIdx.x;
  int b = blockIdx.x;
  int m = min(bcnt[b], BCAP);
  int n0 = b << 7;
  int nb = min(128, NN - n0);
  if (tid < 128) cnt[tid] = 0;
  __syncthreads();
  const unsigned int* bp = bbuf + (size_t)b * BCAP;
  for (int s = tid; s < m; s += 512) {
    unsigned p = bp[s];
    atomicAdd(&cnt[(p >> 17) & 127], 1);
  }
  __syncthreads();
  if (tid < 128) sc[0][tid] = cnt[tid];
  __syncthreads();
  int pp = 0;
  for (int d = 1; d < 128; d <<= 1) {
    if (tid < 128) {
      int v = sc[pp][tid];
      if (tid >= d) v += sc[pp][tid - d];
      sc[pp ^ 1][tid] = v;
    }
    __syncthreads();
    pp ^= 1;
  }
  if (tid < 128) {
    int o = sc[pp][tid] - cnt[tid];
    ofs[tid] = o;
    cur[tid] = o;
  }
  __syncthreads();
  for (int s = tid; s < m; s += 512) {
    unsigned p = bp[s];     // L1-hot second read
    int ld = (p >> 17) & 127;
    int pos = atomicAdd(&cur[ld], 1);
    lcsr[pos] = p & 0x1FFFF;
  }
  __syncthreads();
  int lane = tid & 31;
  int g = tid >> 5;             // 16 groups
  int half = (lane >> 3) & 3;   // which of 4 edges in the iter
  int l8 = lane & 7;            // 16-col chunk within the row
  for (int ln = g; ln < nb; ln += 16) {
    int deg = cnt[ln], beg = ofs[ln];
    float ac[16];
#pragma unroll
    for (int i = 0; i < 16; ++i) ac[i] = 0.f;
#pragma unroll 2
    for (int j = 0; j < deg; j += 4) {
      int idx = j + half;
      uint4 v = {0u, 0u, 0u, 0u};
      if (idx < deg) {
        int s = lcsr[beg + idx];
        v = *(const uint4*)(feat8 + (size_t)s * HID + l8 * 16);
      }
      f2v d;
      d = __builtin_amdgcn_cvt_pk_f32_fp8(v.x, false); ac[0] += d.x;  ac[1] += d.y;
      d = __builtin_amdgcn_cvt_pk_f32_fp8(v.x, true);  ac[2] += d.x;  ac[3] += d.y;
      d = __builtin_amdgcn_cvt_pk_f32_fp8(v.y, false); ac[4] += d.x;  ac[5] += d.y;
      d = __builtin_amdgcn_cvt_pk_f32_fp8(v.y, true);  ac[6] += d.x;  ac[7] += d.y;
      d = __builtin_amdgcn_cvt_pk_f32_fp8(v.z, false); ac[8] += d.x;  ac[9] += d.y;
      d = __builtin_amdgcn_cvt_pk_f32_fp8(v.z, true);  ac[10] += d.x; ac[11] += d.y;
      d = __builtin_amdgcn_cvt_pk_f32_fp8(v.w, false); ac[12] += d.x; ac[13] += d.y;
      d = __builtin_amdgcn_cvt_pk_f32_fp8(v.w, true);  ac[14] += d.x; ac[15] += d.y;
    }
#pragma unroll
    for (int i = 0; i < 16; ++i) {
      ac[i] += __shfl_xor(ac[i], 8);
      ac[i] += __shfl_xor(ac[i], 16);
    }
    if (half == 0) {
      float inv = 1.f / fmaxf((float)deg, 1.f);
      uint4 o0, o1;
      o0.x = packbf(ac[0] * inv, ac[1] * inv);
      o0.y = packbf(ac[2] * inv, ac[3] * inv);
      o0.z = packbf(ac[4] * inv, ac[5] * inv);
      o0.w = packbf(ac[6] * inv, ac[7] * inv);
      o1.x = packbf(ac[8] * inv, ac[9] * inv);
      o1.y = packbf(ac[10] * inv, ac[11] * inv);
      o1.z = packbf(ac[12] * inv, ac[13] * inv);
      o1.w = packbf(ac[14] * inv, ac[15] * inv);
      unsigned short* op = Abuf + (size_t)(n0 + ln) * K2 + l8 * 16;
      *(uint4*)op = o0;
      *(uint4*)(op + 8) = o1;
    }
  }
}

// ---------------- MFMA GEMM: sage = A[N,256] @ Wcat[128,256]^T + bl ----------------
// 128x128 tile per 512-thread block; full Wcat in LDS -> A read ONCE.
// sage stored bf16 to ws scratch; BN2 stats (fp32, exact) fused.
__global__ __launch_bounds__(512) void k_gemm(
    const unsigned short* __restrict__ A, const unsigned short* __restrict__ Wcat,
    const float* __restrict__ bl, unsigned short* __restrict__ sageb,
    float* __restrict__ colSum, float* __restrict__ colSq) {
  __shared__ __align__(16) unsigned short Bsh[HID][264];  // 128 cols x 256 k, +8 pad: 67.6 KB
  __shared__ float redS[8][HID], redQ[8][HID];            // 8 KB
  int tid = threadIdx.x;
  for (int i = tid; i < HID * 32; i += 512) {
    int j = i >> 5;
    int kg = (i & 31) << 3;
    *(s8v*)&Bsh[j][kg] = *(const s8v*)(Wcat + (size_t)j * K2 + kg);
  }
  __syncthreads();
  int w = tid >> 6, l = tid & 63;
  int m16 = l & 15, q = l >> 4;
  int tile = blockIdx.x;
  int row = tile * 128 + w * 16 + m16;
  bool rv = row < NN;
  f4v zero4 = {0.f, 0.f, 0.f, 0.f};
  s8v zero8 = {0, 0, 0, 0, 0, 0, 0, 0};
  f4v acc[8];
#pragma unroll
  for (int nt = 0; nt < 8; ++nt) acc[nt] = zero4;
#pragma unroll
  for (int kt = 0; kt < 8; ++kt) {
    s8v a = zero8;
    if (rv) a = *(const s8v*)(A + (size_t)row * K2 + kt * 32 + q * 8);
#pragma unroll
    for (int nt = 0; nt < 8; ++nt) {
      s8v bfr = *(const s8v*)(&Bsh[nt * 16 + m16][kt * 32 + q * 8]);
      acc[nt] = __builtin_amdgcn_mfma_f32_16x16x32_bf16(a, bfr, acc[nt], 0, 0, 0);
    }
  }
  int rbase = tile * 128 + w * 16 + q * 4;
  float ssum[8], ssq[8];
#pragma unroll
  for (int nt = 0; nt < 8; ++nt) { ssum[nt] = 0.f; ssq[nt] = 0.f; }
#pragma unroll
  for (int nt = 0; nt < 8; ++nt) {
    int col = nt * 16 + m16;
    float bv = bl[col];
#pragma unroll
    for (int r4 = 0; r4 < 4; ++r4) {
      int rr = rbase + r4;
      if (rr < NN) {
        float v = acc[nt][r4] + bv;
        sageb[(size_t)rr * HID + col] = f2bf(v);
        ssum[nt] += v;
        ssq[nt] = fmaf(v, v, ssq[nt]);
      }
    }
  }
#pragma unroll
  for (int nt = 0; nt < 8; ++nt) {
    float s = ssum[nt], qq = ssq[nt];
    s += __shfl_xor(s, 16);
    s += __shfl_xor(s, 32);
    qq += __shfl_xor(qq, 16);
    qq += __shfl_xor(qq, 32);
    if (q == 0) {
      redS[w][nt * 16 + m16] = s;
      redQ[w][nt * 16 + m16] = qq;
    }
  }
  __syncthreads();
  if (tid < HID) {
    float s = 0.f, qq = 0.f;
#pragma unroll
    for (int ww = 0; ww < 8; ++ww) { s += redS[ww][tid]; qq += redQ[ww][tid]; }
    atomicAdd(&colSum[tid], s);
    atomicAdd(&colSq[tid], qq);
  }
}

// ---------------- BN2 apply: read bf16 sage, write fp32 d_out ----------------
__global__ __launch_bounds__(256) void k_bn_apply(const unsigned short* __restrict__ sageb,
                                                  float* __restrict__ out,
                                                  const float* __restrict__ av,
                                                  const float* __restrict__ bv) {
  int i = blockIdx.x * 256 + threadIdx.x;  // oct index: NN*16
  if (i >= NN * 16) return;
  int r = i >> 4, c8 = (i & 15) << 3;
  uint4 sv = *(const uint4*)(sageb + (size_t)r * HID + c8);
  float4 a0 = *(const float4*)(av + c8);
  float4 a1 = *(const float4*)(av + c8 + 4);
  float4 b0 = *(const float4*)(bv + c8);
  float4 b1 = *(const float4*)(bv + c8 + 4);
  float4 o0, o1;
  o0.x = fmaf(bflo(sv.x), a0.x, b0.x);
  o0.y = fmaf(bfhi(sv.x), a0.y, b0.y);
  o0.z = fmaf(bflo(sv.y), a0.z, b0.z);
  o0.w = fmaf(bfhi(sv.y), a0.w, b0.w);
  o1.x = fmaf(bflo(sv.z), a1.x, b1.x);
  o1.y = fmaf(bfhi(sv.z), a1.y, b1.y);
  o1.z = fmaf(bflo(sv.w), a1.z, b1.z);
  o1.w = fmaf(bfhi(sv.w), a1.w, b1.w);
  *(float4*)(out + (size_t)r * HID + c8) = o0;
  *(float4*)(out + (size_t)r * HID + c8 + 4) = o1;
}

extern "C" void kernel_launch(void* const* d_in, const int* in_sizes, int n_in,
                              void* d_out, int out_size, void* d_ws, size_t ws_size,
                              hipStream_t stream) {
  const float* x   = (const float*)d_in[0];
  const int*   ei  = (const int*)d_in[1];
  const float* W1  = (const float*)d_in[2];
  const float* b1  = (const float*)d_in[3];
  const float* g1  = (const float*)d_in[4];
  const float* be1 = (const float*)d_in[5];
  const float* Wl  = (const float*)d_in[6];
  const float* bl  = (const float*)d_in[7];
  const float* Wr  = (const float*)d_in[8];
  const float* g2  = (const float*)d_in[9];
  const float* be2 = (const float*)d_in[10];

  float* feat_out = (float*)d_out;                      // output 0: feat fp32
  float* out2     = (float*)d_out + (size_t)NN * HID;   // output 1: BN2(sage) fp32

  size_t off = 0;
  auto alloc = [&](size_t bytes) -> void* {
    void* p = (char*)d_ws + off;
    off += (bytes + 255) & ~(size_t)255;
    return p;
  };
  unsigned short* Abuf = (unsigned short*)alloc((size_t)NN * K2 * 2);   // [NN][256] bf16: agg|feat
  unsigned char*  feat8 = (unsigned char*)alloc((size_t)NN * HID);      // fp8 e4m3 gather table
  unsigned short* sageb = (unsigned short*)alloc((size_t)NN * HID * 2); // bf16 sage scratch
  unsigned int*   bbuf = (unsigned int*)alloc((size_t)NBUK * BCAP * 4);
  int*            bcur = (int*)alloc((size_t)NBUK * 4);
  float*          stats = (float*)alloc(8 * HID * 4);
  float* colSum1 = stats;
  float* colSq1  = stats + HID;
  float* colSum2 = stats + 2 * HID;
  float* colSq2  = stats + 3 * HID;
  float* a1v     = stats + 4 * HID;
  float* b1v     = stats + 5 * HID;
  float* a2v     = stats + 6 * HID;
  float* b2v     = stats + 7 * HID;
  unsigned short* Wcat = (unsigned short*)alloc((size_t)HID * K2 * 2);
  unsigned short* W1b  = (unsigned short*)alloc((size_t)HID * KP * 2);
  unsigned short* xbf  = (unsigned short*)alloc((size_t)NN * KP * 2);

  k_xcast<<<(NN * 16 + 255) / 256, 256, 0, stream>>>(x, xbf, Wl, Wr, W1, Wcat, W1b, bcur, stats);
  k_bucket<<<(NE + CHUNK - 1) / CHUNK, 512, 0, stream>>>(ei, bcur, bbuf);
  k_proj_gemm<<<512, 256, 0, stream>>>(xbf, W1b, b1, Abuf, colSum1, colSq1);
  k_bn_final<<<1, HID, 0, stream>>>(colSum1, colSq1, g1, be1, a1v, b1v);
  k_apply<<<(NN * 16 + 255) / 256, 256, 0, stream>>>(feat_out, a1v, b1v, Abuf, feat8);
  k_bucket_agg<<<NBUK, 512, 0, stream>>>(bbuf, bcur, feat8, Abuf);
  k_gemm<<<MT2, 512, 0, stream>>>(Abuf, Wcat, bl, sageb, colSum2, colSq2);
  k_bn_final<<<1, HID, 0, stream>>>(colSum2, colSq2, g2, be2, a2v, b2v);
  k_bn_apply<<<(NN * 16 + 255) / 256, 256, 0, stream>>>(sageb, out2, a2v, b2v);
}